// Round 10
// baseline (1019.175 us; speedup 1.0000x reference)
//
#include <hip/hip_runtime.h>
#include <hip/hip_bf16.h>

typedef __hip_bfloat16 bf;
typedef __attribute__((ext_vector_type(4))) float f32x4;
typedef __attribute__((ext_vector_type(8))) __bf16 bf16x8;
typedef __attribute__((ext_vector_type(8))) short short8;

#define NN 12000
#define DD 128
#define HIDC 256
#define BBATCH 512
#define LSEQ 20
#define FFEAT 400
#define FFDIM 512
#define AZ 5
#define AKS (NN / AZ)     // 2400
#define ANT (AKS / 32)    // 75 K-steps per slice (odd)

__device__ __forceinline__ float b2f(bf v) { return __bfloat162float(v); }
__device__ __forceinline__ bf f2b(float v) { return __float2bfloat16(v); }
__device__ __forceinline__ float us2f(unsigned short u) {
    return __uint_as_float(((unsigned int)u) << 16);
}
__device__ __forceinline__ unsigned short f2us(float f) {
    bf h = __float2bfloat16(f);
    return __builtin_bit_cast(unsigned short, h);
}

template<bool F32>
__device__ __forceinline__ short8 ld8(const void* p, long long idx) {
    if (F32) {
        const float* fp = (const float*)p + idx;
        f32x4 u0 = *(const f32x4*)fp;
        f32x4 u1 = *(const f32x4*)(fp + 4);
        short8 s;
        s[0] = (short)f2us(u0[0]); s[1] = (short)f2us(u0[1]);
        s[2] = (short)f2us(u0[2]); s[3] = (short)f2us(u0[3]);
        s[4] = (short)f2us(u1[0]); s[5] = (short)f2us(u1[1]);
        s[6] = (short)f2us(u1[2]); s[7] = (short)f2us(u1[3]);
        return s;
    } else {
        return *(const short8*)((const bf*)p + idx);
    }
}

template<bool F32>
__device__ __forceinline__ bf ldelem(const void* p, long long idx) {
    if (F32) return f2b(((const float*)p)[idx]);
    return ((const bf*)p)[idx];
}

// ---------------------------------------------------------------------------
// adj pass v5: BARRIER-FREE register-blocked GEMM. Each wave independently
// computes a 32-row x 128-col output strip. A and B fragments are loaded
// straight from global memory into MFMA register layout (no LDS):
//   lane: fr = lane&15 (row/col), kq = (lane>>4)*8 (k offset), 16B per frag.
// B (BT, 3 MB) is L2-resident; A streams from HBM/L3 once. Even/odd named
// register double-buffer (static indexing only, rule #20); compiler is free
// to hoist loads across the MFMA block — no barriers anywhere.
// Rationale: R7-R9 PMC showed the LDS-lockstep kernel was latency-bound with
// nothing saturated (hbm 24%, mfma 15%, occ 21%); barriers were the cost.
// ---------------------------------------------------------------------------
__global__ __launch_bounds__(256) void adj_gemm5(
    const bf* __restrict__ A,    // adjb [NN][NN]
    const bf* __restrict__ Bt,   // BT [128][NN]
    float* __restrict__ part)    // [AZ][NN][128]
{
    const int tid = threadIdx.x;
    const int lane = tid & 63;
    const int w = tid >> 6;
    const int z = blockIdx.y;
    const long long k0 = (long long)z * AKS;
    int strip = blockIdx.x * 4 + w;
    if (strip > NN / 32 - 1) strip = NN / 32 - 1;   // dup strip: identical writes, benign
    const int m0 = strip * 32;

    const int fr = lane & 15;
    const int kq = (lane >> 4) * 8;

    const bf* pa0 = A + (long long)(m0 + fr) * NN + k0 + kq;
    const bf* pa1 = A + (long long)(m0 + 16 + fr) * NN + k0 + kq;
    const bf* pb  = Bt + (long long)fr * NN + k0 + kq;

    f32x4 acc[2][8] = {};
    bf16x8 aE[2], bE[8], aO[2], bO[8];

    auto loadE = [&](int t) {
        const long long o = (long long)t * 32;
        aE[0] = *(const bf16x8*)(pa0 + o);
        aE[1] = *(const bf16x8*)(pa1 + o);
        #pragma unroll
        for (int c = 0; c < 8; c++)
            bE[c] = *(const bf16x8*)(pb + (long long)c * (16 * NN) + o);
    };
    auto loadO = [&](int t) {
        const long long o = (long long)t * 32;
        aO[0] = *(const bf16x8*)(pa0 + o);
        aO[1] = *(const bf16x8*)(pa1 + o);
        #pragma unroll
        for (int c = 0; c < 8; c++)
            bO[c] = *(const bf16x8*)(pb + (long long)c * (16 * NN) + o);
    };
    auto mfmaE = [&]() {
        #pragma unroll
        for (int mi = 0; mi < 2; mi++)
            #pragma unroll
            for (int c = 0; c < 8; c++)
                acc[mi][c] = __builtin_amdgcn_mfma_f32_16x16x32_bf16(
                    aE[mi], bE[c], acc[mi][c], 0, 0, 0);
    };
    auto mfmaO = [&]() {
        #pragma unroll
        for (int mi = 0; mi < 2; mi++)
            #pragma unroll
            for (int c = 0; c < 8; c++)
                acc[mi][c] = __builtin_amdgcn_mfma_f32_16x16x32_bf16(
                    aO[mi], bO[c], acc[mi][c], 0, 0, 0);
    };

    loadE(0);
    #pragma unroll 1
    for (int ks = 0; ks < ANT - 1; ks += 2) {
        loadO(ks + 1);
        mfmaE();
        if (ks + 2 < ANT) loadE(ks + 2);
        mfmaO();
    }
    mfmaE();   // ANT odd: final step sits in E regs

    float* C = part + (long long)z * ((long long)NN * 128);
    const int cr0 = (lane >> 4) * 4;
    const int cc = lane & 15;
    #pragma unroll
    for (int mi = 0; mi < 2; mi++) {
        #pragma unroll
        for (int c = 0; c < 8; c++) {
            #pragma unroll
            for (int j = 0; j < 4; j++) {
                int row = m0 + mi * 16 + cr0 + j;
                C[(long long)row * 128 + c * 16 + cc] = acc[mi][c][j];
            }
        }
    }
}

// ---------------------------------------------------------------------------
// Generic batched MFMA GEMM: C = act(alpha * A @ B^T + bias)
// ---------------------------------------------------------------------------
template<bool A_F32, bool B_F32, bool HAS_BIAS, bool RELU, bool OUT_F32, bool SIDE_A>
__global__ __launch_bounds__(256) void gemm128(
    const void* __restrict__ A, int lda, long long sA1, long long sA2,
    const void* __restrict__ Bm, int ldb, long long sB1, long long sB2,
    const float* __restrict__ bias,
    void* __restrict__ Cv, int ldc, long long sC1, long long sC2,
    int M, int N, int K, int tilesN, int zdiv, float alpha,
    bf* __restrict__ sideA)
{
    __shared__ bf As[128][40];
    __shared__ bf Bs[128][40];
    const int tid = threadIdx.x;
    const int z = blockIdx.y;
    const int zq = z / zdiv, zr = z - zq * zdiv;
    const char* Ap = (const char*)A;
    const char* Bp = (const char*)Bm;
    const long long offA = (long long)zq * sA1 + (long long)zr * sA2;
    const long long offB = (long long)zq * sB1 + (long long)zr * sB2;
    const long long offC = (long long)zq * sC1 + (long long)zr * sC2;
    const int tm = blockIdx.x / tilesN, tn = blockIdx.x - tm * tilesN;
    int m0 = tm * 128; if (m0 > M - 128) m0 = M - 128;
    const int n0 = tn * 128;
    const int lane = tid & 63;
    const int wv = tid >> 6;
    const int wr = (wv >> 1) * 64, wc = (wv & 1) * 64;
    const int fr = lane & 15;
    const int kq = (lane >> 4) * 8;
    const int sr = tid >> 2, scol = (tid & 3) * 8;
    f32x4 acc[4][4] = {};

    for (int k0 = 0; k0 < K; k0 += 32) {
        if (k0 + 32 <= K) {
            const long long ia0 = offA + (long long)(m0 + sr) * lda + k0 + scol;
            const long long ia1 = offA + (long long)(m0 + sr + 64) * lda + k0 + scol;
            short8 va0 = ld8<A_F32>(Ap, ia0);
            short8 va1 = ld8<A_F32>(Ap, ia1);
            short8 vb0 = {0,0,0,0,0,0,0,0}, vb1 = {0,0,0,0,0,0,0,0};
            if (n0 + sr < N)      vb0 = ld8<B_F32>(Bp, offB + (long long)(n0 + sr) * ldb + k0 + scol);
            if (n0 + sr + 64 < N) vb1 = ld8<B_F32>(Bp, offB + (long long)(n0 + sr + 64) * ldb + k0 + scol);
            if (SIDE_A) {
                *(short8*)&sideA[ia0] = va0;
                *(short8*)&sideA[ia1] = va1;
            }
            *(short8*)&As[sr][scol] = va0;
            *(short8*)&As[sr + 64][scol] = va1;
            *(short8*)&Bs[sr][scol] = vb0;
            *(short8*)&Bs[sr + 64][scol] = vb1;
        } else {
            bf zv = f2b(0.f);
            for (int i = tid; i < 128 * 32; i += 256) {
                int r = i >> 5, c = i & 31, gk = k0 + c;
                As[r][c] = (gk < K) ? ldelem<A_F32>(Ap, offA + (long long)(m0 + r) * lda + gk) : zv;
                Bs[r][c] = (gk < K && n0 + r < N) ? ldelem<B_F32>(Bp, offB + (long long)(n0 + r) * ldb + gk) : zv;
            }
        }
        __syncthreads();
        bf16x8 af[4], bfg[4];
        #pragma unroll
        for (int i = 0; i < 4; i++) af[i]  = *(const bf16x8*)&As[wr + i * 16 + fr][kq];
        #pragma unroll
        for (int i = 0; i < 4; i++) bfg[i] = *(const bf16x8*)&Bs[wc + i * 16 + fr][kq];
        #pragma unroll
        for (int mi = 0; mi < 4; mi++)
            #pragma unroll
            for (int ni = 0; ni < 4; ni++)
                acc[mi][ni] = __builtin_amdgcn_mfma_f32_16x16x32_bf16(
                    af[mi], bfg[ni], acc[mi][ni], 0, 0, 0);
        __syncthreads();
    }

    const int cr0 = (lane >> 4) * 4;
    const int cc = lane & 15;
    #pragma unroll
    for (int mi = 0; mi < 4; mi++) {
        #pragma unroll
        for (int ni = 0; ni < 4; ni++) {
            int col = n0 + wc + ni * 16 + cc;
            if (col >= N) continue;
            float bv = 0.f;
            if (HAS_BIAS) bv = bias[col];
            #pragma unroll
            for (int j = 0; j < 4; j++) {
                int row = m0 + wr + mi * 16 + cr0 + j;
                float v = acc[mi][ni][j] * alpha + bv;
                if (RELU) v = fmaxf(v, 0.f);
                if (OUT_F32) ((float*)Cv)[offC + (long long)row * ldc + col] = v;
                else ((bf*)Cv)[offC + (long long)row * ldc + col] = f2b(v);
            }
        }
    }
}

template<bool IN_F32>
__global__ __launch_bounds__(256) void transpose_k(
    const void* __restrict__ in, int ldin, long long sI1, long long sI2, int zdiv,
    const float* __restrict__ mulp, int ldmul,
    bf* __restrict__ outp, int ldout, long long sOut,
    int R, int C)
{
    __shared__ bf t[32][33];
    const int z = blockIdx.z;
    const int zq = z / zdiv, zr = z - zq * zdiv;
    const long long offI = (long long)zq * sI1 + (long long)zr * sI2;
    bf* op = outp + (long long)z * sOut;
    int r0 = blockIdx.x * 32, c0 = blockIdx.y * 32;
    int tx = threadIdx.x, ty = threadIdx.y;   // 32 x 8
    #pragma unroll
    for (int i = 0; i < 4; i++) {
        int r = r0 + ty + i * 8, c = c0 + tx;
        bf v = f2b(0.f);
        if (r < R && c < C) {
            v = ldelem<IN_F32>(in, offI + (long long)r * ldin + c);
            if (mulp) v = f2b(b2f(v) * mulp[(long long)r * ldmul + c]);
        }
        t[ty + i * 8][tx] = v;
    }
    __syncthreads();
    #pragma unroll
    for (int i = 0; i < 4; i++) {
        int c = c0 + ty + i * 8, r = r0 + tx;
        if (c < C && r < R) op[(long long)c * ldout + r] = t[tx][ty + i * 8];
    }
}

__global__ __launch_bounds__(256) void reduceK(
    const float* __restrict__ part, const float* __restrict__ bias,
    bf* __restrict__ outp, int total, int nz, long long zs)
{
    int i = blockIdx.x * 256 + threadIdx.x;
    if (i >= total) return;
    float s = 0.f;
    for (int zz = 0; zz < nz; zz++) s += part[(long long)zz * zs + i];
    if (bias) s += bias[i & 127];
    outp[i] = f2b(s);
}

__global__ __launch_bounds__(256) void gather_rows(
    const bf* __restrict__ src, const int* __restrict__ idx,
    bf* __restrict__ dst, int nrows)
{
    int t = blockIdx.x * 256 + threadIdx.x;
    int row = t >> 4, p = t & 15;
    if (row >= nrows) return;
    long long srow = idx[row];
    *(short8*)&dst[(long long)row * 128 + p * 8] =
        *(const short8*)&src[srow * 128 + p * 8];
}

__global__ __launch_bounds__(256) void softmax512(bf* __restrict__ S, int nrows)
{
    int gid = blockIdx.x * 256 + threadIdx.x;
    int wid = gid >> 6, lane = gid & 63;
    if (wid >= nrows) return;
    bf* row = S + (long long)wid * 512;
    short8 raw = *(const short8*)&row[lane * 8];
    float v[8];
    float mx = -3.0e38f;
    #pragma unroll
    for (int j = 0; j < 8; j++) {
        v[j] = us2f((unsigned short)raw[j]);
        mx = fmaxf(mx, v[j]);
    }
    #pragma unroll
    for (int off = 32; off; off >>= 1) mx = fmaxf(mx, __shfl_xor(mx, off, 64));
    float sum = 0.f;
    #pragma unroll
    for (int j = 0; j < 8; j++) { v[j] = __expf(v[j] - mx); sum += v[j]; }
    #pragma unroll
    for (int off = 32; off; off >>= 1) sum += __shfl_xor(sum, off, 64);
    float inv = 1.f / sum;
    short8 o;
    #pragma unroll
    for (int j = 0; j < 8; j++) o[j] = (short)f2us(v[j] * inv);
    *(short8*)&row[lane * 8] = o;
}

__global__ __launch_bounds__(256) void ln_rows(
    const bf* __restrict__ a, const bf* __restrict__ bres,
    const float* __restrict__ sc, const float* __restrict__ bi,
    bf* __restrict__ outp, int nrows)
{
    int gid = blockIdx.x * 256 + threadIdx.x;
    int wid = gid >> 6, lane = gid & 63;
    if (wid >= nrows) return;
    long long base = (long long)wid * 128;
    int i0 = lane * 2, i1 = lane * 2 + 1;
    float x0 = b2f(a[base + i0]) + b2f(bres[base + i0]);
    float x1 = b2f(a[base + i1]) + b2f(bres[base + i1]);
    float s = x0 + x1;
    #pragma unroll
    for (int off = 32; off; off >>= 1) s += __shfl_xor(s, off, 64);
    float mean = s * (1.f / 128.f);
    float d0 = x0 - mean, d1 = x1 - mean;
    float vv = d0 * d0 + d1 * d1;
    #pragma unroll
    for (int off = 32; off; off >>= 1) vv += __shfl_xor(vv, off, 64);
    float inv = rsqrtf(vv * (1.f / 128.f) + 1e-5f);
    outp[base + i0] = f2b(d0 * inv * sc[i0] + bi[i0]);
    outp[base + i1] = f2b(d1 * inv * sc[i1] + bi[i1]);
}

__global__ __launch_bounds__(256) void build_citing(
    const bf* __restrict__ x2, const bf* __restrict__ nf,
    const int* __restrict__ citing, bf* __restrict__ cp)
{
    int i = blockIdx.x * 256 + threadIdx.x;
    if (i >= BBATCH * 256) return;
    int b = i >> 8, d = i & 255;
    float v;
    if (d < 128) {
        float s = 0.f;
        for (int l = 0; l < LSEQ; l++)
            s += b2f(x2[((long long)b * LSEQ + l) * 128 + d]);
        v = s * (1.f / (float)LSEQ);
    } else {
        v = b2f(nf[(long long)citing[b] * 128 + (d - 128)]);
    }
    cp[i] = f2b(v);
}

__global__ __launch_bounds__(256) void build_cited(
    const bf* __restrict__ item, const bf* __restrict__ nf, bf* __restrict__ outp)
{
    int i = blockIdx.x * 256 + threadIdx.x;
    if (i >= NN * 256) return;
    int r = i >> 8, d = i & 255;
    outp[i] = (d < 128) ? item[(long long)r * 128 + d]
                        : nf[(long long)r * 128 + (d - 128)];
}

// ---------------------------------------------------------------------------
extern "C" void kernel_launch(void* const* d_in, const int* in_sizes, int n_in,
                              void* d_out, int out_size, void* d_ws, size_t ws_size,
                              hipStream_t stream)
{
    const float* emb  = (const float*)d_in[0];
    const float* f1w  = (const float*)d_in[1];
    const float* f1b  = (const float*)d_in[2];
    const float* g0w1 = (const float*)d_in[3];  const float* g0b1 = (const float*)d_in[4];
    const float* g0w2 = (const float*)d_in[5];  const float* g0b2 = (const float*)d_in[6];
    const float* g1w1 = (const float*)d_in[7];  const float* g1b1 = (const float*)d_in[8];
    const float* g1w2 = (const float*)d_in[9];  const float* g1b2 = (const float*)d_in[10];
    const float* ipw  = (const float*)d_in[11]; const float* ipb  = (const float*)d_in[12];
    const float* opw  = (const float*)d_in[13]; const float* opb  = (const float*)d_in[14];
    const float* ln1s = (const float*)d_in[15]; const float* ln1b = (const float*)d_in[16];
    const float* ff1w = (const float*)d_in[17]; const float* ff1b = (const float*)d_in[18];
    const float* ff2w = (const float*)d_in[19]; const float* ff2b = (const float*)d_in[20];
    const float* ln2s = (const float*)d_in[21]; const float* ln2b = (const float*)d_in[22];
    const float* adj  = (const float*)d_in[23];
    const float* nfe  = (const float*)d_in[24];
    const int* citing = (const int*)d_in[26];
    const int* useqs  = (const int*)d_in[28];
    float* outp = (float*)d_out;

    size_t off = 0;
    auto carve = [&](size_t bytes) -> char* {
        char* p = (char*)d_ws + off;
        off += (bytes + 255) & ~(size_t)255;
        return p;
    };
    bf* adjb = (bf*)carve((size_t)NN * NN * 2);       // bf16 copy of adj (288 MB)
    bf* nf   = (bf*)carve((size_t)NN * DD * 2);
    bf* bufP = (bf*)carve((size_t)NN * DD * 2);
    bf* bufQ = (bf*)carve((size_t)NN * DD * 2);
    bf* BT   = (bf*)carve((size_t)NN * DD * 2);       // transposed [128][12000]
    bf* Hbuf = (bf*)carve((size_t)NN * HIDC * 2);
    float* part = (float*)carve((size_t)AZ * NN * DD * 4);   // 30 MB
    bf* seq  = (bf*)carve((size_t)10240 * DD * 2);
    bf* qkv  = (bf*)carve((size_t)10240 * 384 * 2);
    bf* Sb   = (bf*)carve((size_t)80 * 512 * 512 * 2);
    bf* w10T = (bf*)carve((size_t)DD * HIDC * 2);
    bf* w20T = (bf*)carve((size_t)DD * HIDC * 2);
    bf* w11T = (bf*)carve((size_t)DD * HIDC * 2);
    bf* w21T = (bf*)carve((size_t)DD * HIDC * 2);
    // aliases (regions dead by the time these are live)
    bf* x1ln = (bf*)Hbuf;
    bf* cp   = (bf*)((char*)Hbuf + (size_t)10240 * DD * 2);
    char* pr = (char*)part;
    bf* VT   = (bf*)pr; pr += (size_t)80 * 32 * 512 * 2;
    bf* o_   = (bf*)pr; pr += (size_t)10240 * DD * 2;
    bf* o2   = (bf*)pr; pr += (size_t)10240 * DD * 2;
    bf* ffh  = (bf*)pr; pr += (size_t)10240 * FFDIM * 2;
    bf* ff2o = (bf*)pr; pr += (size_t)10240 * DD * 2;
    bf* x2   = (bf*)pr; pr += (size_t)10240 * DD * 2;
    bf* cited= (bf*)pr; pr += (size_t)NN * 256 * 2;

    dim3 tb(256), tt(32, 8);
    const long long NM = (long long)NN * DD;   // 1,536,000

    // GCN weight transposes: W1[D,HID] -> w1T[HID,D];  W2[HID,D] -> w2T[D,HID]
    transpose_k<true><<<dim3(4, 8, 1), tt, 0, stream>>>(g0w1, HIDC, 0, 0, 1, nullptr, 0, w10T, DD, 0, DD, HIDC);
    transpose_k<true><<<dim3(8, 4, 1), tt, 0, stream>>>(g0w2, DD, 0, 0, 1, nullptr, 0, w20T, HIDC, 0, HIDC, DD);
    transpose_k<true><<<dim3(4, 8, 1), tt, 0, stream>>>(g1w1, HIDC, 0, 0, 1, nullptr, 0, w11T, DD, 0, DD, HIDC);
    transpose_k<true><<<dim3(8, 4, 1), tt, 0, stream>>>(g1w2, DD, 0, 0, 1, nullptr, 0, w21T, HIDC, 0, HIDC, DD);

    // nf = node_feature @ f1_w^T + f1_b    [12000,128]
    gemm128<true, true, true, false, false, false><<<dim3(94, 1), tb, 0, stream>>>(
        nfe, FFEAT, 0, 0, f1w, FFEAT, 0, 0, f1b,
        nf, DD, 0, 0, NN, DD, FFEAT, 1, 1, 1.f, nullptr);
    // BT = (emb .* nf)^T   [128][12000]
    transpose_k<false><<<dim3(375, 4, 1), tt, 0, stream>>>(nf, DD, 0, 0, 1, emb, DD, BT, NN, 0, NN, DD);

    const float* biases2[2] = { g0b2, g1b2 };
    const float* biases1[2] = { g0b1, g1b1 };
    const bf* w1T[2] = { w10T, w11T };
    const bf* w2T[2] = { w20T, w21T };
    bf* xout[2] = { bufP, bufQ };   // x1 -> bufP ; item -> bufQ

    for (int g = 0; g < 2; g++) {
        // t = A @ x  (x^T staged in BT), K-split 5
        if (g == 0) {
            // first adj pass reads f32 adj and side-writes the bf16 copy
            gemm128<true, false, false, false, true, true><<<dim3(94, AZ), tb, 0, stream>>>(
                adj, NN, AKS, 0, BT, NN, AKS, 0, nullptr,
                part, DD, NM, 0, NN, DD, AKS, 1, 1, 1.f, adjb);
        } else {
            adj_gemm5<<<dim3(94, AZ), tb, 0, stream>>>(adjb, BT, part);
        }
        bf* tbuf = (g == 0) ? bufP : bufQ;
        reduceK<<<dim3((NM + 255) / 256), tb, 0, stream>>>(part, nullptr, tbuf, (int)NM, AZ, NM);
        // h = relu(t @ W1 + b1)   [12000,256]
        gemm128<false, false, true, true, false, false><<<dim3(188, 1), tb, 0, stream>>>(
            tbuf, DD, 0, 0, w1T[g], DD, 0, 0, biases1[g],
            Hbuf, HIDC, 0, 0, NN, HIDC, DD, 2, 1, 1.f, nullptr);
        // t2 = h @ W2            [12000,128]
        bf* t2buf = (g == 0) ? bufQ : bufP;
        gemm128<false, false, false, false, false, false><<<dim3(94, 1), tb, 0, stream>>>(
            Hbuf, HIDC, 0, 0, w2T[g], HIDC, 0, 0, nullptr,
            t2buf, DD, 0, 0, NN, DD, HIDC, 1, 1, 1.f, nullptr);
        // BT = t2^T
        transpose_k<false><<<dim3(375, 4, 1), tt, 0, stream>>>(t2buf, DD, 0, 0, 1, nullptr, 0, BT, NN, 0, NN, DD);
        // x' = A @ t2 + b2  (barrier-free register-blocked adj kernel)
        adj_gemm5<<<dim3(94, AZ), tb, 0, stream>>>(adjb, BT, part);
        reduceK<<<dim3((NM + 255) / 256), tb, 0, stream>>>(part, biases2[g], xout[g], (int)NM, AZ, NM);
        if (g == 0) {
            // BT = x1^T for next module
            transpose_k<false><<<dim3(375, 4, 1), tt, 0, stream>>>(bufP, DD, 0, 0, 1, nullptr, 0, BT, NN, 0, NN, DD);
        }
    }
    bf* item = bufQ;

    // seq = item[u_seqs]   [10240,128]
    gather_rows<<<dim3(640), tb, 0, stream>>>(item, useqs, seq, 10240);
    // qkv = seq @ in_proj_w^T + b   [10240,384]
    gemm128<false, true, true, false, false, false><<<dim3(240, 1), tb, 0, stream>>>(
        seq, DD, 0, 0, ipw, DD, 0, 0, ipb,
        qkv, 384, 0, 0, 10240, 384, DD, 3, 1, 1.f, nullptr);
    // VT[z=(n,h)][d][t] from qkv V slice
    transpose_k<false><<<dim3(16, 1, 80), tt, 0, stream>>>(
        qkv + 256, 7680, 384, 32, 4, nullptr, 0, VT, 512, 16384, 512, 32);
    // S[z] = alpha * Q_z @ K_z^T   (z = n*4+h), M=N=512, K=32
    gemm128<false, false, false, false, false, false><<<dim3(16, 80), tb, 0, stream>>>(
        qkv, 7680, 384, 32, qkv + 128, 7680, 384, 32, nullptr,
        Sb, 512, (long long)4 * 262144, 262144, 512, 512, 32, 4, 4, 0.17677669529663687f, nullptr);
    // softmax rows (in place)
    softmax512<<<dim3(10240), tb, 0, stream>>>(Sb, 80 * 512);
    // o = P @ V   -> o[s][n][h*32+d]
    gemm128<false, false, false, false, false, false><<<dim3(4, 80), tb, 0, stream>>>(
        Sb, 512, (long long)4 * 262144, 262144, VT, 512, (long long)4 * 16384, 16384, nullptr,
        o_, 2560, 128, 32, 512, 32, 512, 1, 4, 1.f, nullptr);
    // o2 = o @ out_proj^T + b
    gemm128<false, true, true, false, false, false><<<dim3(80, 1), tb, 0, stream>>>(
        o_, DD, 0, 0, opw, DD, 0, 0, opb,
        o2, DD, 0, 0, 10240, DD, DD, 1, 1, 1.f, nullptr);
    // x1 = LN(seq + o2)
    ln_rows<<<dim3(2560), tb, 0, stream>>>(seq, o2, ln1s, ln1b, x1ln, 10240);
    // ffh = relu(x1 @ ff1^T + b)   [10240,512]
    gemm128<false, true, true, true, false, false><<<dim3(320, 1), tb, 0, stream>>>(
        x1ln, DD, 0, 0, ff1w, DD, 0, 0, ff1b,
        ffh, FFDIM, 0, 0, 10240, FFDIM, DD, 4, 1, 1.f, nullptr);
    // ff2 = ffh @ ff2^T + b
    gemm128<false, true, true, false, false, false><<<dim3(80, 1), tb, 0, stream>>>(
        ffh, FFDIM, 0, 0, ff2w, FFDIM, 0, 0, ff2b,
        ff2o, DD, 0, 0, 10240, DD, FFDIM, 1, 1, 1.f, nullptr);
    // x2 = LN(x1 + ff2)
    ln_rows<<<dim3(2560), tb, 0, stream>>>(x1ln, ff2o, ln2s, ln2b, x2, 10240);
    // citing_paper / cited_paper
    build_citing<<<dim3(512), tb, 0, stream>>>(x2, nf, citing, cp);
    build_cited<<<dim3(12000), tb, 0, stream>>>(item, nf, cited);
    // scores = cp @ cited^T   [512,12000]  (f32 out)
    gemm128<false, false, false, false, true, false><<<dim3(376, 1), tb, 0, stream>>>(
        cp, 256, 0, 0, cited, 256, 0, 0, nullptr,
        outp, NN, 0, 0, BBATCH, NN, 256, 94, 1, 1.f, nullptr);
}

// Round 11
// 770.164 us; speedup vs baseline: 1.3233x; 1.3233x over previous
//
#include <hip/hip_runtime.h>
#include <hip/hip_bf16.h>

typedef __hip_bfloat16 bf;
typedef __attribute__((ext_vector_type(4))) float f32x4;
typedef __attribute__((ext_vector_type(8))) __bf16 bf16x8;
typedef __attribute__((ext_vector_type(8))) short short8;

#define NN 12000
#define DD 128
#define HIDC 256
#define BBATCH 512
#define LSEQ 20
#define FFEAT 400
#define FFDIM 512
#define AZ 5
#define AKS (NN / AZ)     // 2400 = 37*64 + 32

__device__ __forceinline__ float b2f(bf v) { return __bfloat162float(v); }
__device__ __forceinline__ bf f2b(float v) { return __float2bfloat16(v); }
__device__ __forceinline__ float us2f(unsigned short u) {
    return __uint_as_float(((unsigned int)u) << 16);
}
__device__ __forceinline__ unsigned short f2us(float f) {
    bf h = __float2bfloat16(f);
    return __builtin_bit_cast(unsigned short, h);
}

__device__ __forceinline__ void gload_lds16(const bf* g, bf* l) {
    __builtin_amdgcn_global_load_lds(
        (__attribute__((address_space(1))) void*)(g),
        (__attribute__((address_space(3))) void*)(l),
        16, 0, 0);
}

template<bool F32>
__device__ __forceinline__ short8 ld8(const void* p, long long idx) {
    if (F32) {
        const float* fp = (const float*)p + idx;
        f32x4 u0 = *(const f32x4*)fp;
        f32x4 u1 = *(const f32x4*)(fp + 4);
        short8 s;
        s[0] = (short)f2us(u0[0]); s[1] = (short)f2us(u0[1]);
        s[2] = (short)f2us(u0[2]); s[3] = (short)f2us(u0[3]);
        s[4] = (short)f2us(u1[0]); s[5] = (short)f2us(u1[1]);
        s[6] = (short)f2us(u1[2]); s[7] = (short)f2us(u1[3]);
        return s;
    } else {
        return *(const short8*)((const bf*)p + idx);
    }
}

template<bool F32>
__device__ __forceinline__ bf ldelem(const void* p, long long idx) {
    if (F32) return f2b(((const float*)p)[idx]);
    return ((const bf*)p)[idx];
}

// ---------------------------------------------------------------------------
// adj pass v6: BK=64 K-steps (38 barrier-pairs vs 75) on the verified
// counted-vmcnt 2-deep pipeline. Full stages: 128x64 tiles, swizzle
// chunk ^= (row&7) over 8x16B chunks (source pre-swizzled, LDS linear,
// rule #21). Tail stage (last 32 cols of the 2400 slice) reuses the
// R4-verified BK=32 swizzle in a compact 64B/row region of buffer 1.
// vmcnt ladder: 8 (steady), 4 (tail in flight), 0 (last).
// ---------------------------------------------------------------------------
__global__ __launch_bounds__(256) void adj_gemm6(
    const bf* __restrict__ A,    // adjb [NN][NN]
    const bf* __restrict__ Bt,   // BT [128][NN]
    float* __restrict__ part)    // [AZ][NN][128]
{
    alignas(16) __shared__ bf As[2][128 * 64];
    alignas(16) __shared__ bf Bs[2][128 * 64];
    const int tid = threadIdx.x;
    const int lane = tid & 63;
    const int w = tid >> 6;
    const int z = blockIdx.y;
    const long long k0 = (long long)z * AKS;
    int m0 = blockIdx.x * 128;
    if (m0 > NN - 128) m0 = NN - 128;

    // full-stage staging: issue i covers rows rbase..rbase+7 (rbase=32w+8i)
    // lane L -> row rbase+(L>>3), phys chunk L&7; source chunk (L&7)^(L>>3)
    const int rowi = lane >> 3;
    const int chks = (lane & 7) ^ rowi;
    const bf* gA[4]; const bf* gB[4]; bf* lA[4]; bf* lB[4];
    #pragma unroll
    for (int i = 0; i < 4; i++) {
        int rbase = 32 * w + 8 * i;
        gA[i] = A  + (long long)(m0 + rbase + rowi) * NN + k0 + chks * 8;
        gB[i] = Bt + (long long)(rbase + rowi) * NN + k0 + chks * 8;
        lA[i] = &As[0][rbase * 64];
        lB[i] = &Bs[0][rbase * 64];
    }
    // tail staging: 32 cols, 16 rows/issue, R4 swizzle, compact 64B/row in buf1
    const int rowiT = lane >> 2;
    const int chksT = (lane & 3) ^ ((lane >> 3) & 3);
    const bf* gAT[2]; const bf* gBT[2]; bf* lAT[2]; bf* lBT[2];
    #pragma unroll
    for (int i = 0; i < 2; i++) {
        int rbase = 32 * w + 16 * i;
        gAT[i] = A  + (long long)(m0 + rbase + rowiT) * NN + k0 + 2368 + chksT * 8;
        gBT[i] = Bt + (long long)(rbase + rowiT) * NN + k0 + 2368 + chksT * 8;
        lAT[i] = &As[1][rbase * 32];
        lBT[i] = &Bs[1][rbase * 32];
    }

    const int wr = (w >> 1) * 64, wc = (w & 1) * 64;
    const int fr = lane & 15;
    const int kq = lane >> 4;
    int aoff[2][4], boff[2][4], aoffT[4], boffT[4];
    #pragma unroll
    for (int i = 0; i < 4; i++) {
        int ra = wr + i * 16 + fr, rb = wc + i * 16 + fr;
        #pragma unroll
        for (int s = 0; s < 2; s++) {
            aoff[s][i] = ra * 64 + ((s * 4 + kq) ^ (ra & 7)) * 8;
            boff[s][i] = rb * 64 + ((s * 4 + kq) ^ (rb & 7)) * 8;
        }
        aoffT[i] = ra * 32 + (kq ^ ((ra >> 1) & 3)) * 8;
        boffT[i] = rb * 32 + (kq ^ ((rb >> 1) & 3)) * 8;
    }
    f32x4 acc[4][4] = {};

    auto stage64 = [&](int t, int b) {
        const long long go = (long long)t * 64;
        const int bo = b * (128 * 64);
        #pragma unroll
        for (int i = 0; i < 4; i++) {
            gload_lds16(gA[i] + go, lA[i] + bo);
            gload_lds16(gB[i] + go, lB[i] + bo);
        }
    };
    auto stageTail = [&]() {
        #pragma unroll
        for (int i = 0; i < 2; i++) {
            gload_lds16(gAT[i], lAT[i]);
            gload_lds16(gBT[i], lBT[i]);
        }
    };
    auto compute64 = [&](int b) {
        const bf* Ab = &As[b][0];
        const bf* Bb = &Bs[b][0];
        #pragma unroll
        for (int s = 0; s < 2; s++) {
            bf16x8 af[4], bfr[4];
            #pragma unroll
            for (int i = 0; i < 4; i++) af[i]  = *(const bf16x8*)(Ab + aoff[s][i]);
            #pragma unroll
            for (int i = 0; i < 4; i++) bfr[i] = *(const bf16x8*)(Bb + boff[s][i]);
            #pragma unroll
            for (int mi = 0; mi < 4; mi++)
                #pragma unroll
                for (int ni = 0; ni < 4; ni++)
                    acc[mi][ni] = __builtin_amdgcn_mfma_f32_16x16x32_bf16(
                        af[mi], bfr[ni], acc[mi][ni], 0, 0, 0);
        }
    };

    // prologue: stages 0,1 (16 issues/wave in flight)
    stage64(0, 0);
    stage64(1, 1);

    #pragma unroll 1
    for (int t = 0; t < 36; t++) {
        asm volatile("s_waitcnt vmcnt(8)" ::: "memory");   // stage t resident
        __builtin_amdgcn_s_barrier();
        __builtin_amdgcn_sched_barrier(0);
        compute64(t & 1);
        __builtin_amdgcn_s_barrier();                      // all waves done reading
        if (t < 35) stage64(t + 2, t & 1);
        else        stageTail();                           // stage 37 -> buf1 compact
    }
    // t = 36 (buf0): tail (4 issues) still in flight
    asm volatile("s_waitcnt vmcnt(4)" ::: "memory");
    __builtin_amdgcn_s_barrier();
    __builtin_amdgcn_sched_barrier(0);
    compute64(0);
    __builtin_amdgcn_s_barrier();
    // t = 37: tail
    asm volatile("s_waitcnt vmcnt(0)" ::: "memory");
    __builtin_amdgcn_s_barrier();
    __builtin_amdgcn_sched_barrier(0);
    {
        bf16x8 af[4], bfr[4];
        #pragma unroll
        for (int i = 0; i < 4; i++) af[i]  = *(const bf16x8*)(&As[1][0] + aoffT[i]);
        #pragma unroll
        for (int i = 0; i < 4; i++) bfr[i] = *(const bf16x8*)(&Bs[1][0] + boffT[i]);
        #pragma unroll
        for (int mi = 0; mi < 4; mi++)
            #pragma unroll
            for (int ni = 0; ni < 4; ni++)
                acc[mi][ni] = __builtin_amdgcn_mfma_f32_16x16x32_bf16(
                    af[mi], bfr[ni], acc[mi][ni], 0, 0, 0);
    }

    float* C = part + (long long)z * ((long long)NN * 128);
    const int cr0 = (lane >> 4) * 4;
    const int cc = lane & 15;
    #pragma unroll
    for (int mi = 0; mi < 4; mi++) {
        #pragma unroll
        for (int ni = 0; ni < 4; ni++) {
            int col = wc + ni * 16 + cc;
            #pragma unroll
            for (int j = 0; j < 4; j++) {
                int row = m0 + wr + mi * 16 + cr0 + j;
                C[(long long)row * 128 + col] = acc[mi][ni][j];
            }
        }
    }
}

// ---------------------------------------------------------------------------
// Generic batched MFMA GEMM: C = act(alpha * A @ B^T + bias)
// ---------------------------------------------------------------------------
template<bool A_F32, bool B_F32, bool HAS_BIAS, bool RELU, bool OUT_F32, bool SIDE_A>
__global__ __launch_bounds__(256) void gemm128(
    const void* __restrict__ A, int lda, long long sA1, long long sA2,
    const void* __restrict__ Bm, int ldb, long long sB1, long long sB2,
    const float* __restrict__ bias,
    void* __restrict__ Cv, int ldc, long long sC1, long long sC2,
    int M, int N, int K, int tilesN, int zdiv, float alpha,
    bf* __restrict__ sideA)
{
    __shared__ bf As[128][40];
    __shared__ bf Bs[128][40];
    const int tid = threadIdx.x;
    const int z = blockIdx.y;
    const int zq = z / zdiv, zr = z - zq * zdiv;
    const char* Ap = (const char*)A;
    const char* Bp = (const char*)Bm;
    const long long offA = (long long)zq * sA1 + (long long)zr * sA2;
    const long long offB = (long long)zq * sB1 + (long long)zr * sB2;
    const long long offC = (long long)zq * sC1 + (long long)zr * sC2;
    const int tm = blockIdx.x / tilesN, tn = blockIdx.x - tm * tilesN;
    int m0 = tm * 128; if (m0 > M - 128) m0 = M - 128;
    const int n0 = tn * 128;
    const int lane = tid & 63;
    const int wv = tid >> 6;
    const int wr = (wv >> 1) * 64, wc = (wv & 1) * 64;
    const int fr = lane & 15;
    const int kq = (lane >> 4) * 8;
    const int sr = tid >> 2, scol = (tid & 3) * 8;
    f32x4 acc[4][4] = {};

    for (int k0 = 0; k0 < K; k0 += 32) {
        if (k0 + 32 <= K) {
            const long long ia0 = offA + (long long)(m0 + sr) * lda + k0 + scol;
            const long long ia1 = offA + (long long)(m0 + sr + 64) * lda + k0 + scol;
            short8 va0 = ld8<A_F32>(Ap, ia0);
            short8 va1 = ld8<A_F32>(Ap, ia1);
            short8 vb0 = {0,0,0,0,0,0,0,0}, vb1 = {0,0,0,0,0,0,0,0};
            if (n0 + sr < N)      vb0 = ld8<B_F32>(Bp, offB + (long long)(n0 + sr) * ldb + k0 + scol);
            if (n0 + sr + 64 < N) vb1 = ld8<B_F32>(Bp, offB + (long long)(n0 + sr + 64) * ldb + k0 + scol);
            if (SIDE_A) {
                *(short8*)&sideA[ia0] = va0;
                *(short8*)&sideA[ia1] = va1;
            }
            *(short8*)&As[sr][scol] = va0;
            *(short8*)&As[sr + 64][scol] = va1;
            *(short8*)&Bs[sr][scol] = vb0;
            *(short8*)&Bs[sr + 64][scol] = vb1;
        } else {
            bf zv = f2b(0.f);
            for (int i = tid; i < 128 * 32; i += 256) {
                int r = i >> 5, c = i & 31, gk = k0 + c;
                As[r][c] = (gk < K) ? ldelem<A_F32>(Ap, offA + (long long)(m0 + r) * lda + gk) : zv;
                Bs[r][c] = (gk < K && n0 + r < N) ? ldelem<B_F32>(Bp, offB + (long long)(n0 + r) * ldb + gk) : zv;
            }
        }
        __syncthreads();
        bf16x8 af[4], bfg[4];
        #pragma unroll
        for (int i = 0; i < 4; i++) af[i]  = *(const bf16x8*)&As[wr + i * 16 + fr][kq];
        #pragma unroll
        for (int i = 0; i < 4; i++) bfg[i] = *(const bf16x8*)&Bs[wc + i * 16 + fr][kq];
        #pragma unroll
        for (int mi = 0; mi < 4; mi++)
            #pragma unroll
            for (int ni = 0; ni < 4; ni++)
                acc[mi][ni] = __builtin_amdgcn_mfma_f32_16x16x32_bf16(
                    af[mi], bfg[ni], acc[mi][ni], 0, 0, 0);
        __syncthreads();
    }

    const int cr0 = (lane >> 4) * 4;
    const int cc = lane & 15;
    #pragma unroll
    for (int mi = 0; mi < 4; mi++) {
        #pragma unroll
        for (int ni = 0; ni < 4; ni++) {
            int col = n0 + wc + ni * 16 + cc;
            if (col >= N) continue;
            float bv = 0.f;
            if (HAS_BIAS) bv = bias[col];
            #pragma unroll
            for (int j = 0; j < 4; j++) {
                int row = m0 + wr + mi * 16 + cr0 + j;
                float v = acc[mi][ni][j] * alpha + bv;
                if (RELU) v = fmaxf(v, 0.f);
                if (OUT_F32) ((float*)Cv)[offC + (long long)row * ldc + col] = v;
                else ((bf*)Cv)[offC + (long long)row * ldc + col] = f2b(v);
            }
        }
    }
}

template<bool IN_F32>
__global__ __launch_bounds__(256) void transpose_k(
    const void* __restrict__ in, int ldin, long long sI1, long long sI2, int zdiv,
    const float* __restrict__ mulp, int ldmul,
    bf* __restrict__ outp, int ldout, long long sOut,
    int R, int C)
{
    __shared__ bf t[32][33];
    const int z = blockIdx.z;
    const int zq = z / zdiv, zr = z - zq * zdiv;
    const long long offI = (long long)zq * sI1 + (long long)zr * sI2;
    bf* op = outp + (long long)z * sOut;
    int r0 = blockIdx.x * 32, c0 = blockIdx.y * 32;
    int tx = threadIdx.x, ty = threadIdx.y;   // 32 x 8
    #pragma unroll
    for (int i = 0; i < 4; i++) {
        int r = r0 + ty + i * 8, c = c0 + tx;
        bf v = f2b(0.f);
        if (r < R && c < C) {
            v = ldelem<IN_F32>(in, offI + (long long)r * ldin + c);
            if (mulp) v = f2b(b2f(v) * mulp[(long long)r * ldmul + c]);
        }
        t[ty + i * 8][tx] = v;
    }
    __syncthreads();
    #pragma unroll
    for (int i = 0; i < 4; i++) {
        int c = c0 + ty + i * 8, r = r0 + tx;
        if (c < C && r < R) op[(long long)c * ldout + r] = t[tx][ty + i * 8];
    }
}

__global__ __launch_bounds__(256) void reduceK(
    const float* __restrict__ part, const float* __restrict__ bias,
    bf* __restrict__ outp, int total, int nz, long long zs)
{
    int i = blockIdx.x * 256 + threadIdx.x;
    if (i >= total) return;
    float s = 0.f;
    for (int zz = 0; zz < nz; zz++) s += part[(long long)zz * zs + i];
    if (bias) s += bias[i & 127];
    outp[i] = f2b(s);
}

__global__ __launch_bounds__(256) void gather_rows(
    const bf* __restrict__ src, const int* __restrict__ idx,
    bf* __restrict__ dst, int nrows)
{
    int t = blockIdx.x * 256 + threadIdx.x;
    int row = t >> 4, p = t & 15;
    if (row >= nrows) return;
    long long srow = idx[row];
    *(short8*)&dst[(long long)row * 128 + p * 8] =
        *(const short8*)&src[srow * 128 + p * 8];
}

__global__ __launch_bounds__(256) void softmax512(bf* __restrict__ S, int nrows)
{
    int gid = blockIdx.x * 256 + threadIdx.x;
    int wid = gid >> 6, lane = gid & 63;
    if (wid >= nrows) return;
    bf* row = S + (long long)wid * 512;
    short8 raw = *(const short8*)&row[lane * 8];
    float v[8];
    float mx = -3.0e38f;
    #pragma unroll
    for (int j = 0; j < 8; j++) {
        v[j] = us2f((unsigned short)raw[j]);
        mx = fmaxf(mx, v[j]);
    }
    #pragma unroll
    for (int off = 32; off; off >>= 1) mx = fmaxf(mx, __shfl_xor(mx, off, 64));
    float sum = 0.f;
    #pragma unroll
    for (int j = 0; j < 8; j++) { v[j] = __expf(v[j] - mx); sum += v[j]; }
    #pragma unroll
    for (int off = 32; off; off >>= 1) sum += __shfl_xor(sum, off, 64);
    float inv = 1.f / sum;
    short8 o;
    #pragma unroll
    for (int j = 0; j < 8; j++) o[j] = (short)f2us(v[j] * inv);
    *(short8*)&row[lane * 8] = o;
}

__global__ __launch_bounds__(256) void ln_rows(
    const bf* __restrict__ a, const bf* __restrict__ bres,
    const float* __restrict__ sc, const float* __restrict__ bi,
    bf* __restrict__ outp, int nrows)
{
    int gid = blockIdx.x * 256 + threadIdx.x;
    int wid = gid >> 6, lane = gid & 63;
    if (wid >= nrows) return;
    long long base = (long long)wid * 128;
    int i0 = lane * 2, i1 = lane * 2 + 1;
    float x0 = b2f(a[base + i0]) + b2f(bres[base + i0]);
    float x1 = b2f(a[base + i1]) + b2f(bres[base + i1]);
    float s = x0 + x1;
    #pragma unroll
    for (int off = 32; off; off >>= 1) s += __shfl_xor(s, off, 64);
    float mean = s * (1.f / 128.f);
    float d0 = x0 - mean, d1 = x1 - mean;
    float vv = d0 * d0 + d1 * d1;
    #pragma unroll
    for (int off = 32; off; off >>= 1) vv += __shfl_xor(vv, off, 64);
    float inv = rsqrtf(vv * (1.f / 128.f) + 1e-5f);
    outp[base + i0] = f2b(d0 * inv * sc[i0] + bi[i0]);
    outp[base + i1] = f2b(d1 * inv * sc[i1] + bi[i1]);
}

__global__ __launch_bounds__(256) void build_citing(
    const bf* __restrict__ x2, const bf* __restrict__ nf,
    const int* __restrict__ citing, bf* __restrict__ cp)
{
    int i = blockIdx.x * 256 + threadIdx.x;
    if (i >= BBATCH * 256) return;
    int b = i >> 8, d = i & 255;
    float v;
    if (d < 128) {
        float s = 0.f;
        for (int l = 0; l < LSEQ; l++)
            s += b2f(x2[((long long)b * LSEQ + l) * 128 + d]);
        v = s * (1.f / (float)LSEQ);
    } else {
        v = b2f(nf[(long long)citing[b] * 128 + (d - 128)]);
    }
    cp[i] = f2b(v);
}

__global__ __launch_bounds__(256) void build_cited(
    const bf* __restrict__ item, const bf* __restrict__ nf, bf* __restrict__ outp)
{
    int i = blockIdx.x * 256 + threadIdx.x;
    if (i >= NN * 256) return;
    int r = i >> 8, d = i & 255;
    outp[i] = (d < 128) ? item[(long long)r * 128 + d]
                        : nf[(long long)r * 128 + (d - 128)];
}

// ---------------------------------------------------------------------------
extern "C" void kernel_launch(void* const* d_in, const int* in_sizes, int n_in,
                              void* d_out, int out_size, void* d_ws, size_t ws_size,
                              hipStream_t stream)
{
    const float* emb  = (const float*)d_in[0];
    const float* f1w  = (const float*)d_in[1];
    const float* f1b  = (const float*)d_in[2];
    const float* g0w1 = (const float*)d_in[3];  const float* g0b1 = (const float*)d_in[4];
    const float* g0w2 = (const float*)d_in[5];  const float* g0b2 = (const float*)d_in[6];
    const float* g1w1 = (const float*)d_in[7];  const float* g1b1 = (const float*)d_in[8];
    const float* g1w2 = (const float*)d_in[9];  const float* g1b2 = (const float*)d_in[10];
    const float* ipw  = (const float*)d_in[11]; const float* ipb  = (const float*)d_in[12];
    const float* opw  = (const float*)d_in[13]; const float* opb  = (const float*)d_in[14];
    const float* ln1s = (const float*)d_in[15]; const float* ln1b = (const float*)d_in[16];
    const float* ff1w = (const float*)d_in[17]; const float* ff1b = (const float*)d_in[18];
    const float* ff2w = (const float*)d_in[19]; const float* ff2b = (const float*)d_in[20];
    const float* ln2s = (const float*)d_in[21]; const float* ln2b = (const float*)d_in[22];
    const float* adj  = (const float*)d_in[23];
    const float* nfe  = (const float*)d_in[24];
    const int* citing = (const int*)d_in[26];
    const int* useqs  = (const int*)d_in[28];
    float* outp = (float*)d_out;

    size_t off = 0;
    auto carve = [&](size_t bytes) -> char* {
        char* p = (char*)d_ws + off;
        off += (bytes + 255) & ~(size_t)255;
        return p;
    };
    bf* adjb = (bf*)carve((size_t)NN * NN * 2);       // bf16 copy of adj (288 MB)
    bf* nf   = (bf*)carve((size_t)NN * DD * 2);
    bf* bufP = (bf*)carve((size_t)NN * DD * 2);
    bf* bufQ = (bf*)carve((size_t)NN * DD * 2);
    bf* BT   = (bf*)carve((size_t)NN * DD * 2);       // transposed [128][12000]
    bf* Hbuf = (bf*)carve((size_t)NN * HIDC * 2);
    float* part = (float*)carve((size_t)AZ * NN * DD * 4);   // 30 MB
    bf* seq  = (bf*)carve((size_t)10240 * DD * 2);
    bf* qkv  = (bf*)carve((size_t)10240 * 384 * 2);
    bf* Sb   = (bf*)carve((size_t)80 * 512 * 512 * 2);
    bf* w10T = (bf*)carve((size_t)DD * HIDC * 2);
    bf* w20T = (bf*)carve((size_t)DD * HIDC * 2);
    bf* w11T = (bf*)carve((size_t)DD * HIDC * 2);
    bf* w21T = (bf*)carve((size_t)DD * HIDC * 2);
    // aliases (regions dead by the time these are live)
    bf* x1ln = (bf*)Hbuf;
    bf* cp   = (bf*)((char*)Hbuf + (size_t)10240 * DD * 2);
    char* pr = (char*)part;
    bf* VT   = (bf*)pr; pr += (size_t)80 * 32 * 512 * 2;
    bf* o_   = (bf*)pr; pr += (size_t)10240 * DD * 2;
    bf* o2   = (bf*)pr; pr += (size_t)10240 * DD * 2;
    bf* ffh  = (bf*)pr; pr += (size_t)10240 * FFDIM * 2;
    bf* ff2o = (bf*)pr; pr += (size_t)10240 * DD * 2;
    bf* x2   = (bf*)pr; pr += (size_t)10240 * DD * 2;
    bf* cited= (bf*)pr; pr += (size_t)NN * 256 * 2;

    dim3 tb(256), tt(32, 8);
    const long long NM = (long long)NN * DD;   // 1,536,000

    // GCN weight transposes: W1[D,HID] -> w1T[HID,D];  W2[HID,D] -> w2T[D,HID]
    transpose_k<true><<<dim3(4, 8, 1), tt, 0, stream>>>(g0w1, HIDC, 0, 0, 1, nullptr, 0, w10T, DD, 0, DD, HIDC);
    transpose_k<true><<<dim3(8, 4, 1), tt, 0, stream>>>(g0w2, DD, 0, 0, 1, nullptr, 0, w20T, HIDC, 0, HIDC, DD);
    transpose_k<true><<<dim3(4, 8, 1), tt, 0, stream>>>(g1w1, HIDC, 0, 0, 1, nullptr, 0, w11T, DD, 0, DD, HIDC);
    transpose_k<true><<<dim3(8, 4, 1), tt, 0, stream>>>(g1w2, DD, 0, 0, 1, nullptr, 0, w21T, HIDC, 0, HIDC, DD);

    // nf = node_feature @ f1_w^T + f1_b    [12000,128]
    gemm128<true, true, true, false, false, false><<<dim3(94, 1), tb, 0, stream>>>(
        nfe, FFEAT, 0, 0, f1w, FFEAT, 0, 0, f1b,
        nf, DD, 0, 0, NN, DD, FFEAT, 1, 1, 1.f, nullptr);
    // BT = (emb .* nf)^T   [128][12000]
    transpose_k<false><<<dim3(375, 4, 1), tt, 0, stream>>>(nf, DD, 0, 0, 1, emb, DD, BT, NN, 0, NN, DD);

    const float* biases2[2] = { g0b2, g1b2 };
    const float* biases1[2] = { g0b1, g1b1 };
    const bf* w1T[2] = { w10T, w11T };
    const bf* w2T[2] = { w20T, w21T };
    bf* xout[2] = { bufP, bufQ };   // x1 -> bufP ; item -> bufQ

    for (int g = 0; g < 2; g++) {
        // t = A @ x  (x^T staged in BT), K-split 5
        if (g == 0) {
            // first adj pass reads f32 adj and side-writes the bf16 copy
            gemm128<true, false, false, false, true, true><<<dim3(94, AZ), tb, 0, stream>>>(
                adj, NN, AKS, 0, BT, NN, AKS, 0, nullptr,
                part, DD, NM, 0, NN, DD, AKS, 1, 1, 1.f, adjb);
        } else {
            adj_gemm6<<<dim3(94, AZ), tb, 0, stream>>>(adjb, BT, part);
        }
        bf* tbuf = (g == 0) ? bufP : bufQ;
        reduceK<<<dim3((NM + 255) / 256), tb, 0, stream>>>(part, nullptr, tbuf, (int)NM, AZ, NM);
        // h = relu(t @ W1 + b1)   [12000,256]
        gemm128<false, false, true, true, false, false><<<dim3(188, 1), tb, 0, stream>>>(
            tbuf, DD, 0, 0, w1T[g], DD, 0, 0, biases1[g],
            Hbuf, HIDC, 0, 0, NN, HIDC, DD, 2, 1, 1.f, nullptr);
        // t2 = h @ W2            [12000,128]
        bf* t2buf = (g == 0) ? bufQ : bufP;
        gemm128<false, false, false, false, false, false><<<dim3(94, 1), tb, 0, stream>>>(
            Hbuf, HIDC, 0, 0, w2T[g], HIDC, 0, 0, nullptr,
            t2buf, DD, 0, 0, NN, DD, HIDC, 1, 1, 1.f, nullptr);
        // BT = t2^T
        transpose_k<false><<<dim3(375, 4, 1), tt, 0, stream>>>(t2buf, DD, 0, 0, 1, nullptr, 0, BT, NN, 0, NN, DD);
        // x' = A @ t2 + b2  (BK=64 pipelined adj kernel)
        adj_gemm6<<<dim3(94, AZ), tb, 0, stream>>>(adjb, BT, part);
        reduceK<<<dim3((NM + 255) / 256), tb, 0, stream>>>(part, biases2[g], xout[g], (int)NM, AZ, NM);
        if (g == 0) {
            // BT = x1^T for next module
            transpose_k<false><<<dim3(375, 4, 1), tt, 0, stream>>>(bufP, DD, 0, 0, 1, nullptr, 0, BT, NN, 0, NN, DD);
        }
    }
    bf* item = bufQ;

    // seq = item[u_seqs]   [10240,128]
    gather_rows<<<dim3(640), tb, 0, stream>>>(item, useqs, seq, 10240);
    // qkv = seq @ in_proj_w^T + b   [10240,384]
    gemm128<false, true, true, false, false, false><<<dim3(240, 1), tb, 0, stream>>>(
        seq, DD, 0, 0, ipw, DD, 0, 0, ipb,
        qkv, 384, 0, 0, 10240, 384, DD, 3, 1, 1.f, nullptr);
    // VT[z=(n,h)][d][t] from qkv V slice
    transpose_k<false><<<dim3(16, 1, 80), tt, 0, stream>>>(
        qkv + 256, 7680, 384, 32, 4, nullptr, 0, VT, 512, 16384, 512, 32);
    // S[z] = alpha * Q_z @ K_z^T   (z = n*4+h), M=N=512, K=32
    gemm128<false, false, false, false, false, false><<<dim3(16, 80), tb, 0, stream>>>(
        qkv, 7680, 384, 32, qkv + 128, 7680, 384, 32, nullptr,
        Sb, 512, (long long)4 * 262144, 262144, 512, 512, 32, 4, 4, 0.17677669529663687f, nullptr);
    // softmax rows (in place)
    softmax512<<<dim3(10240), tb, 0, stream>>>(Sb, 80 * 512);
    // o = P @ V   -> o[s][n][h*32+d]
    gemm128<false, false, false, false, false, false><<<dim3(4, 80), tb, 0, stream>>>(
        Sb, 512, (long long)4 * 262144, 262144, VT, 512, (long long)4 * 16384, 16384, nullptr,
        o_, 2560, 128, 32, 512, 32, 512, 1, 4, 1.f, nullptr);
    // o2 = o @ out_proj^T + b
    gemm128<false, true, true, false, false, false><<<dim3(80, 1), tb, 0, stream>>>(
        o_, DD, 0, 0, opw, DD, 0, 0, opb,
        o2, DD, 0, 0, 10240, DD, DD, 1, 1, 1.f, nullptr);
    // x1 = LN(seq + o2)
    ln_rows<<<dim3(2560), tb, 0, stream>>>(seq, o2, ln1s, ln1b, x1ln, 10240);
    // ffh = relu(x1 @ ff1^T + b)   [10240,512]
    gemm128<false, true, true, true, false, false><<<dim3(320, 1), tb, 0, stream>>>(
        x1ln, DD, 0, 0, ff1w, DD, 0, 0, ff1b,
        ffh, FFDIM, 0, 0, 10240, FFDIM, DD, 4, 1, 1.f, nullptr);
    // ff2 = ffh @ ff2^T + b
    gemm128<false, true, true, false, false, false><<<dim3(80, 1), tb, 0, stream>>>(
        ffh, FFDIM, 0, 0, ff2w, FFDIM, 0, 0, ff2b,
        ff2o, DD, 0, 0, 10240, DD, FFDIM, 1, 1, 1.f, nullptr);
    // x2 = LN(x1 + ff2)
    ln_rows<<<dim3(2560), tb, 0, stream>>>(x1ln, ff2o, ln2s, ln2b, x2, 10240);
    // citing_paper / cited_paper
    build_citing<<<dim3(512), tb, 0, stream>>>(x2, nf, citing, cp);
    build_cited<<<dim3(12000), tb, 0, stream>>>(item, nf, cited);
    // scores = cp @ cited^T   [512,12000]  (f32 out)
    gemm128<false, false, false, false, true, false><<<dim3(376, 1), tb, 0, stream>>>(
        cp, 256, 0, 0, cited, 256, 0, 0, nullptr,
        outp, NN, 0, 0, BBATCH, NN, 256, 94, 1, 1.f, nullptr);
}

// Round 12
// 767.798 us; speedup vs baseline: 1.3274x; 1.0031x over previous
//
#include <hip/hip_runtime.h>
#include <hip/hip_bf16.h>

typedef __hip_bfloat16 bf;
typedef __attribute__((ext_vector_type(4))) float f32x4;
typedef __attribute__((ext_vector_type(8))) __bf16 bf16x8;
typedef __attribute__((ext_vector_type(8))) short short8;

#define NN 12000
#define DD 128
#define HIDC 256
#define BBATCH 512
#define LSEQ 20
#define FFEAT 400
#define FFDIM 512
#define AZ 5
#define AKS (NN / AZ)     // 2400 = 37*64 + 32

__device__ __forceinline__ float b2f(bf v) { return __bfloat162float(v); }
__device__ __forceinline__ bf f2b(float v) { return __float2bfloat16(v); }
__device__ __forceinline__ float us2f(unsigned short u) {
    return __uint_as_float(((unsigned int)u) << 16);
}
__device__ __forceinline__ unsigned short f2us(float f) {
    bf h = __float2bfloat16(f);
    return __builtin_bit_cast(unsigned short, h);
}

__device__ __forceinline__ void gload_lds16(const bf* g, bf* l) {
    __builtin_amdgcn_global_load_lds(
        (__attribute__((address_space(1))) void*)(g),
        (__attribute__((address_space(3))) void*)(l),
        16, 0, 0);
}

template<bool F32>
__device__ __forceinline__ short8 ld8(const void* p, long long idx) {
    if (F32) {
        const float* fp = (const float*)p + idx;
        f32x4 u0 = *(const f32x4*)fp;
        f32x4 u1 = *(const f32x4*)(fp + 4);
        short8 s;
        s[0] = (short)f2us(u0[0]); s[1] = (short)f2us(u0[1]);
        s[2] = (short)f2us(u0[2]); s[3] = (short)f2us(u0[3]);
        s[4] = (short)f2us(u1[0]); s[5] = (short)f2us(u1[1]);
        s[6] = (short)f2us(u1[2]); s[7] = (short)f2us(u1[3]);
        return s;
    } else {
        return *(const short8*)((const bf*)p + idx);
    }
}

template<bool F32>
__device__ __forceinline__ bf ldelem(const void* p, long long idx) {
    if (F32) return f2b(((const float*)p)[idx]);
    return ((const bf*)p)[idx];
}

// ---------------------------------------------------------------------------
// adj pass v7: BK=64, 3-buffer LDS ring, ONE barrier per K-step (vs 2 in v6).
// Race-freedom: stage(t+2) targets buf((t+2)%3) == buf((t-1)%3); every wave's
// step-(t-1) ds_reads complete before it passes the step-t barrier (each read
// has a compiler wait before its MFMA use, which precedes the stage issue in
// program order). Data-ready: own-wave counted vmcnt + barrier => all waves'
// gload_lds for tile t landed. 512 threads (8 waves, 4x2 grid, 32x64/wave),
// LDS 96 KB -> 1 block/CU = 8 waves/CU (same residency as v6's 2x4-wave).
// Swizzle formulas identical to the R11-verified v6 (row-dependent only).
// vmcnt ladder: 4 (steady, 4 issues/stage), 2 (tail in flight), 0 (last).
// ---------------------------------------------------------------------------
__global__ __launch_bounds__(512) void adj_gemm7(
    const bf* __restrict__ A,    // adjb [NN][NN]
    const bf* __restrict__ Bt,   // BT [128][NN]
    float* __restrict__ part)    // [AZ][NN][128]
{
    alignas(16) __shared__ bf As[3][128 * 64];
    alignas(16) __shared__ bf Bs[3][128 * 64];
    const int tid = threadIdx.x;
    const int lane = tid & 63;
    const int w = tid >> 6;                       // 0..7
    const int z = blockIdx.y;
    const long long k0 = (long long)z * AKS;
    int m0 = blockIdx.x * 128;
    if (m0 > NN - 128) m0 = NN - 128;

    // full-stage staging: wave w covers rows 16w..16w+15 of A and of B
    // (2 issues each); lane L -> row rbase+(L>>3), source chunk (L&7)^(L>>3)
    const int rowi = lane >> 3;
    const int chks = (lane & 7) ^ rowi;
    const bf* gA[2]; const bf* gB[2]; int lo[2];
    #pragma unroll
    for (int i = 0; i < 2; i++) {
        int rbase = 16 * w + 8 * i;
        gA[i] = A  + (long long)(m0 + rbase + rowi) * NN + k0 + chks * 8;
        gB[i] = Bt + (long long)(rbase + rowi) * NN + k0 + chks * 8;
        lo[i] = rbase * 64;
    }
    // tail staging (last 32 cols): 16 rows/issue (1 per matrix per wave),
    // R4 swizzle, compact 32 elem/row region at the start of buffer 1
    const int rowiT = lane >> 2;
    const int chksT = (lane & 3) ^ ((lane >> 3) & 3);
    const bf* gAT = A  + (long long)(m0 + 16 * w + rowiT) * NN + k0 + 2368 + chksT * 8;
    const bf* gBT = Bt + (long long)(16 * w + rowiT) * NN + k0 + 2368 + chksT * 8;
    const int loT = (16 * w) * 32;

    const int wr = (w >> 1) * 32, wc = (w & 1) * 64;
    const int fr = lane & 15;
    const int kq = lane >> 4;
    int aoff[2][2], boff[2][4], aoffT[2], boffT[4];
    #pragma unroll
    for (int mi = 0; mi < 2; mi++) {
        int ra = wr + mi * 16 + fr;
        aoff[0][mi] = ra * 64 + ((kq)     ^ (ra & 7)) * 8;
        aoff[1][mi] = ra * 64 + ((4 + kq) ^ (ra & 7)) * 8;
        aoffT[mi]   = ra * 32 + (kq ^ ((ra >> 1) & 3)) * 8;
    }
    #pragma unroll
    for (int ni = 0; ni < 4; ni++) {
        int rb = wc + ni * 16 + fr;
        boff[0][ni] = rb * 64 + ((kq)     ^ (rb & 7)) * 8;
        boff[1][ni] = rb * 64 + ((4 + kq) ^ (rb & 7)) * 8;
        boffT[ni]   = rb * 32 + (kq ^ ((rb >> 1) & 3)) * 8;
    }
    f32x4 acc[2][4] = {};

    auto stage64 = [&](int t, int b) {
        const long long go = (long long)t * 64;
        const int bo = b * (128 * 64);
        #pragma unroll
        for (int i = 0; i < 2; i++) {
            gload_lds16(gA[i] + go, &As[0][0] + bo + lo[i]);
            gload_lds16(gB[i] + go, &Bs[0][0] + bo + lo[i]);
        }
    };
    auto stageTail = [&]() {
        gload_lds16(gAT, &As[1][0] + loT);
        gload_lds16(gBT, &Bs[1][0] + loT);
    };
    auto compute64 = [&](int b) {
        const bf* Ab = &As[0][0] + b * (128 * 64);
        const bf* Bb = &Bs[0][0] + b * (128 * 64);
        #pragma unroll
        for (int s = 0; s < 2; s++) {
            bf16x8 af[2], bfr[4];
            #pragma unroll
            for (int mi = 0; mi < 2; mi++) af[mi]  = *(const bf16x8*)(Ab + aoff[s][mi]);
            #pragma unroll
            for (int ni = 0; ni < 4; ni++) bfr[ni] = *(const bf16x8*)(Bb + boff[s][ni]);
            #pragma unroll
            for (int mi = 0; mi < 2; mi++)
                #pragma unroll
                for (int ni = 0; ni < 4; ni++)
                    acc[mi][ni] = __builtin_amdgcn_mfma_f32_16x16x32_bf16(
                        af[mi], bfr[ni], acc[mi][ni], 0, 0, 0);
        }
    };

    // prologue: 8 issues/wave in flight
    stage64(0, 0);
    stage64(1, 1);

    #pragma unroll 1
    for (int t = 0; t < 36; t++) {
        asm volatile("s_waitcnt vmcnt(4)" ::: "memory");   // stage t resident
        __builtin_amdgcn_s_barrier();                      // all waves' stages landed
        __builtin_amdgcn_sched_barrier(0);
        compute64(t % 3);
        if (t < 35) stage64(t + 2, (t + 2) % 3);           // overwrites buf read at t-1
        else        stageTail();                           // stage 37 -> buf1 compact
    }
    // t = 36 (buf 0): tail (2 issues) still in flight
    asm volatile("s_waitcnt vmcnt(2)" ::: "memory");
    __builtin_amdgcn_s_barrier();
    __builtin_amdgcn_sched_barrier(0);
    compute64(0);
    // t = 37: tail (buf1 compact)
    asm volatile("s_waitcnt vmcnt(0)" ::: "memory");
    __builtin_amdgcn_s_barrier();
    __builtin_amdgcn_sched_barrier(0);
    {
        bf16x8 af[2], bfr[4];
        #pragma unroll
        for (int mi = 0; mi < 2; mi++) af[mi]  = *(const bf16x8*)(&As[1][0] + aoffT[mi]);
        #pragma unroll
        for (int ni = 0; ni < 4; ni++) bfr[ni] = *(const bf16x8*)(&Bs[1][0] + boffT[ni]);
        #pragma unroll
        for (int mi = 0; mi < 2; mi++)
            #pragma unroll
            for (int ni = 0; ni < 4; ni++)
                acc[mi][ni] = __builtin_amdgcn_mfma_f32_16x16x32_bf16(
                    af[mi], bfr[ni], acc[mi][ni], 0, 0, 0);
    }

    float* C = part + (long long)z * ((long long)NN * 128);
    const int cr0 = (lane >> 4) * 4;
    const int cc = lane & 15;
    #pragma unroll
    for (int mi = 0; mi < 2; mi++) {
        #pragma unroll
        for (int ni = 0; ni < 4; ni++) {
            int col = wc + ni * 16 + cc;
            #pragma unroll
            for (int j = 0; j < 4; j++) {
                int row = m0 + wr + mi * 16 + cr0 + j;
                C[(long long)row * 128 + col] = acc[mi][ni][j];
            }
        }
    }
}

// ---------------------------------------------------------------------------
// Generic batched MFMA GEMM: C = act(alpha * A @ B^T + bias)
// ---------------------------------------------------------------------------
template<bool A_F32, bool B_F32, bool HAS_BIAS, bool RELU, bool OUT_F32, bool SIDE_A>
__global__ __launch_bounds__(256) void gemm128(
    const void* __restrict__ A, int lda, long long sA1, long long sA2,
    const void* __restrict__ Bm, int ldb, long long sB1, long long sB2,
    const float* __restrict__ bias,
    void* __restrict__ Cv, int ldc, long long sC1, long long sC2,
    int M, int N, int K, int tilesN, int zdiv, float alpha,
    bf* __restrict__ sideA)
{
    __shared__ bf As[128][40];
    __shared__ bf Bs[128][40];
    const int tid = threadIdx.x;
    const int z = blockIdx.y;
    const int zq = z / zdiv, zr = z - zq * zdiv;
    const char* Ap = (const char*)A;
    const char* Bp = (const char*)Bm;
    const long long offA = (long long)zq * sA1 + (long long)zr * sA2;
    const long long offB = (long long)zq * sB1 + (long long)zr * sB2;
    const long long offC = (long long)zq * sC1 + (long long)zr * sC2;
    const int tm = blockIdx.x / tilesN, tn = blockIdx.x - tm * tilesN;
    int m0 = tm * 128; if (m0 > M - 128) m0 = M - 128;
    const int n0 = tn * 128;
    const int lane = tid & 63;
    const int wv = tid >> 6;
    const int wr = (wv >> 1) * 64, wc = (wv & 1) * 64;
    const int fr = lane & 15;
    const int kq = (lane >> 4) * 8;
    const int sr = tid >> 2, scol = (tid & 3) * 8;
    f32x4 acc[4][4] = {};

    for (int k0 = 0; k0 < K; k0 += 32) {
        if (k0 + 32 <= K) {
            const long long ia0 = offA + (long long)(m0 + sr) * lda + k0 + scol;
            const long long ia1 = offA + (long long)(m0 + sr + 64) * lda + k0 + scol;
            short8 va0 = ld8<A_F32>(Ap, ia0);
            short8 va1 = ld8<A_F32>(Ap, ia1);
            short8 vb0 = {0,0,0,0,0,0,0,0}, vb1 = {0,0,0,0,0,0,0,0};
            if (n0 + sr < N)      vb0 = ld8<B_F32>(Bp, offB + (long long)(n0 + sr) * ldb + k0 + scol);
            if (n0 + sr + 64 < N) vb1 = ld8<B_F32>(Bp, offB + (long long)(n0 + sr + 64) * ldb + k0 + scol);
            if (SIDE_A) {
                *(short8*)&sideA[ia0] = va0;
                *(short8*)&sideA[ia1] = va1;
            }
            *(short8*)&As[sr][scol] = va0;
            *(short8*)&As[sr + 64][scol] = va1;
            *(short8*)&Bs[sr][scol] = vb0;
            *(short8*)&Bs[sr + 64][scol] = vb1;
        } else {
            bf zv = f2b(0.f);
            for (int i = tid; i < 128 * 32; i += 256) {
                int r = i >> 5, c = i & 31, gk = k0 + c;
                As[r][c] = (gk < K) ? ldelem<A_F32>(Ap, offA + (long long)(m0 + r) * lda + gk) : zv;
                Bs[r][c] = (gk < K && n0 + r < N) ? ldelem<B_F32>(Bp, offB + (long long)(n0 + r) * ldb + gk) : zv;
            }
        }
        __syncthreads();
        bf16x8 af[4], bfg[4];
        #pragma unroll
        for (int i = 0; i < 4; i++) af[i]  = *(const bf16x8*)&As[wr + i * 16 + fr][kq];
        #pragma unroll
        for (int i = 0; i < 4; i++) bfg[i] = *(const bf16x8*)&Bs[wc + i * 16 + fr][kq];
        #pragma unroll
        for (int mi = 0; mi < 4; mi++)
            #pragma unroll
            for (int ni = 0; ni < 4; ni++)
                acc[mi][ni] = __builtin_amdgcn_mfma_f32_16x16x32_bf16(
                    af[mi], bfg[ni], acc[mi][ni], 0, 0, 0);
        __syncthreads();
    }

    const int cr0 = (lane >> 4) * 4;
    const int cc = lane & 15;
    #pragma unroll
    for (int mi = 0; mi < 4; mi++) {
        #pragma unroll
        for (int ni = 0; ni < 4; ni++) {
            int col = n0 + wc + ni * 16 + cc;
            if (col >= N) continue;
            float bv = 0.f;
            if (HAS_BIAS) bv = bias[col];
            #pragma unroll
            for (int j = 0; j < 4; j++) {
                int row = m0 + wr + mi * 16 + cr0 + j;
                float v = acc[mi][ni][j] * alpha + bv;
                if (RELU) v = fmaxf(v, 0.f);
                if (OUT_F32) ((float*)Cv)[offC + (long long)row * ldc + col] = v;
                else ((bf*)Cv)[offC + (long long)row * ldc + col] = f2b(v);
            }
        }
    }
}

template<bool IN_F32>
__global__ __launch_bounds__(256) void transpose_k(
    const void* __restrict__ in, int ldin, long long sI1, long long sI2, int zdiv,
    const float* __restrict__ mulp, int ldmul,
    bf* __restrict__ outp, int ldout, long long sOut,
    int R, int C)
{
    __shared__ bf t[32][33];
    const int z = blockIdx.z;
    const int zq = z / zdiv, zr = z - zq * zdiv;
    const long long offI = (long long)zq * sI1 + (long long)zr * sI2;
    bf* op = outp + (long long)z * sOut;
    int r0 = blockIdx.x * 32, c0 = blockIdx.y * 32;
    int tx = threadIdx.x, ty = threadIdx.y;   // 32 x 8
    #pragma unroll
    for (int i = 0; i < 4; i++) {
        int r = r0 + ty + i * 8, c = c0 + tx;
        bf v = f2b(0.f);
        if (r < R && c < C) {
            v = ldelem<IN_F32>(in, offI + (long long)r * ldin + c);
            if (mulp) v = f2b(b2f(v) * mulp[(long long)r * ldmul + c]);
        }
        t[ty + i * 8][tx] = v;
    }
    __syncthreads();
    #pragma unroll
    for (int i = 0; i < 4; i++) {
        int c = c0 + ty + i * 8, r = r0 + tx;
        if (c < C && r < R) op[(long long)c * ldout + r] = t[tx][ty + i * 8];
    }
}

__global__ __launch_bounds__(256) void reduceK(
    const float* __restrict__ part, const float* __restrict__ bias,
    bf* __restrict__ outp, int total, int nz, long long zs)
{
    int i = blockIdx.x * 256 + threadIdx.x;
    if (i >= total) return;
    float s = 0.f;
    for (int zz = 0; zz < nz; zz++) s += part[(long long)zz * zs + i];
    if (bias) s += bias[i & 127];
    outp[i] = f2b(s);
}

__global__ __launch_bounds__(256) void gather_rows(
    const bf* __restrict__ src, const int* __restrict__ idx,
    bf* __restrict__ dst, int nrows)
{
    int t = blockIdx.x * 256 + threadIdx.x;
    int row = t >> 4, p = t & 15;
    if (row >= nrows) return;
    long long srow = idx[row];
    *(short8*)&dst[(long long)row * 128 + p * 8] =
        *(const short8*)&src[srow * 128 + p * 8];
}

__global__ __launch_bounds__(256) void softmax512(bf* __restrict__ S, int nrows)
{
    int gid = blockIdx.x * 256 + threadIdx.x;
    int wid = gid >> 6, lane = gid & 63;
    if (wid >= nrows) return;
    bf* row = S + (long long)wid * 512;
    short8 raw = *(const short8*)&row[lane * 8];
    float v[8];
    float mx = -3.0e38f;
    #pragma unroll
    for (int j = 0; j < 8; j++) {
        v[j] = us2f((unsigned short)raw[j]);
        mx = fmaxf(mx, v[j]);
    }
    #pragma unroll
    for (int off = 32; off; off >>= 1) mx = fmaxf(mx, __shfl_xor(mx, off, 64));
    float sum = 0.f;
    #pragma unroll
    for (int j = 0; j < 8; j++) { v[j] = __expf(v[j] - mx); sum += v[j]; }
    #pragma unroll
    for (int off = 32; off; off >>= 1) sum += __shfl_xor(sum, off, 64);
    float inv = 1.f / sum;
    short8 o;
    #pragma unroll
    for (int j = 0; j < 8; j++) o[j] = (short)f2us(v[j] * inv);
    *(short8*)&row[lane * 8] = o;
}

__global__ __launch_bounds__(256) void ln_rows(
    const bf* __restrict__ a, const bf* __restrict__ bres,
    const float* __restrict__ sc, const float* __restrict__ bi,
    bf* __restrict__ outp, int nrows)
{
    int gid = blockIdx.x * 256 + threadIdx.x;
    int wid = gid >> 6, lane = gid & 63;
    if (wid >= nrows) return;
    long long base = (long long)wid * 128;
    int i0 = lane * 2, i1 = lane * 2 + 1;
    float x0 = b2f(a[base + i0]) + b2f(bres[base + i0]);
    float x1 = b2f(a[base + i1]) + b2f(bres[base + i1]);
    float s = x0 + x1;
    #pragma unroll
    for (int off = 32; off; off >>= 1) s += __shfl_xor(s, off, 64);
    float mean = s * (1.f / 128.f);
    float d0 = x0 - mean, d1 = x1 - mean;
    float vv = d0 * d0 + d1 * d1;
    #pragma unroll
    for (int off = 32; off; off >>= 1) vv += __shfl_xor(vv, off, 64);
    float inv = rsqrtf(vv * (1.f / 128.f) + 1e-5f);
    outp[base + i0] = f2b(d0 * inv * sc[i0] + bi[i0]);
    outp[base + i1] = f2b(d1 * inv * sc[i1] + bi[i1]);
}

__global__ __launch_bounds__(256) void build_citing(
    const bf* __restrict__ x2, const bf* __restrict__ nf,
    const int* __restrict__ citing, bf* __restrict__ cp)
{
    int i = blockIdx.x * 256 + threadIdx.x;
    if (i >= BBATCH * 256) return;
    int b = i >> 8, d = i & 255;
    float v;
    if (d < 128) {
        float s = 0.f;
        for (int l = 0; l < LSEQ; l++)
            s += b2f(x2[((long long)b * LSEQ + l) * 128 + d]);
        v = s * (1.f / (float)LSEQ);
    } else {
        v = b2f(nf[(long long)citing[b] * 128 + (d - 128)]);
    }
    cp[i] = f2b(v);
}

__global__ __launch_bounds__(256) void build_cited(
    const bf* __restrict__ item, const bf* __restrict__ nf, bf* __restrict__ outp)
{
    int i = blockIdx.x * 256 + threadIdx.x;
    if (i >= NN * 256) return;
    int r = i >> 8, d = i & 255;
    outp[i] = (d < 128) ? item[(long long)r * 128 + d]
                        : nf[(long long)r * 128 + (d - 128)];
}

// ---------------------------------------------------------------------------
extern "C" void kernel_launch(void* const* d_in, const int* in_sizes, int n_in,
                              void* d_out, int out_size, void* d_ws, size_t ws_size,
                              hipStream_t stream)
{
    const float* emb  = (const float*)d_in[0];
    const float* f1w  = (const float*)d_in[1];
    const float* f1b  = (const float*)d_in[2];
    const float* g0w1 = (const float*)d_in[3];  const float* g0b1 = (const float*)d_in[4];
    const float* g0w2 = (const float*)d_in[5];  const float* g0b2 = (const float*)d_in[6];
    const float* g1w1 = (const float*)d_in[7];  const float* g1b1 = (const float*)d_in[8];
    const float* g1w2 = (const float*)d_in[9];  const float* g1b2 = (const float*)d_in[10];
    const float* ipw  = (const float*)d_in[11]; const float* ipb  = (const float*)d_in[12];
    const float* opw  = (const float*)d_in[13]; const float* opb  = (const float*)d_in[14];
    const float* ln1s = (const float*)d_in[15]; const float* ln1b = (const float*)d_in[16];
    const float* ff1w = (const float*)d_in[17]; const float* ff1b = (const float*)d_in[18];
    const float* ff2w = (const float*)d_in[19]; const float* ff2b = (const float*)d_in[20];
    const float* ln2s = (const float*)d_in[21]; const float* ln2b = (const float*)d_in[22];
    const float* adj  = (const float*)d_in[23];
    const float* nfe  = (const float*)d_in[24];
    const int* citing = (const int*)d_in[26];
    const int* useqs  = (const int*)d_in[28];
    float* outp = (float*)d_out;

    size_t off = 0;
    auto carve = [&](size_t bytes) -> char* {
        char* p = (char*)d_ws + off;
        off += (bytes + 255) & ~(size_t)255;
        return p;
    };
    bf* adjb = (bf*)carve((size_t)NN * NN * 2);       // bf16 copy of adj (288 MB)
    bf* nf   = (bf*)carve((size_t)NN * DD * 2);
    bf* bufP = (bf*)carve((size_t)NN * DD * 2);
    bf* bufQ = (bf*)carve((size_t)NN * DD * 2);
    bf* BT   = (bf*)carve((size_t)NN * DD * 2);       // transposed [128][12000]
    bf* Hbuf = (bf*)carve((size_t)NN * HIDC * 2);
    float* part = (float*)carve((size_t)AZ * NN * DD * 4);   // 30 MB
    bf* seq  = (bf*)carve((size_t)10240 * DD * 2);
    bf* qkv  = (bf*)carve((size_t)10240 * 384 * 2);
    bf* Sb   = (bf*)carve((size_t)80 * 512 * 512 * 2);
    bf* w10T = (bf*)carve((size_t)DD * HIDC * 2);
    bf* w20T = (bf*)carve((size_t)DD * HIDC * 2);
    bf* w11T = (bf*)carve((size_t)DD * HIDC * 2);
    bf* w21T = (bf*)carve((size_t)DD * HIDC * 2);
    // aliases (regions dead by the time these are live)
    bf* x1ln = (bf*)Hbuf;
    bf* cp   = (bf*)((char*)Hbuf + (size_t)10240 * DD * 2);
    char* pr = (char*)part;
    bf* VT   = (bf*)pr; pr += (size_t)80 * 32 * 512 * 2;
    bf* o_   = (bf*)pr; pr += (size_t)10240 * DD * 2;
    bf* o2   = (bf*)pr; pr += (size_t)10240 * DD * 2;
    bf* ffh  = (bf*)pr; pr += (size_t)10240 * FFDIM * 2;
    bf* ff2o = (bf*)pr; pr += (size_t)10240 * DD * 2;
    bf* x2   = (bf*)pr; pr += (size_t)10240 * DD * 2;
    bf* cited= (bf*)pr; pr += (size_t)NN * 256 * 2;

    dim3 tb(256), tb512(512), tt(32, 8);
    const long long NM = (long long)NN * DD;   // 1,536,000

    // GCN weight transposes: W1[D,HID] -> w1T[HID,D];  W2[HID,D] -> w2T[D,HID]
    transpose_k<true><<<dim3(4, 8, 1), tt, 0, stream>>>(g0w1, HIDC, 0, 0, 1, nullptr, 0, w10T, DD, 0, DD, HIDC);
    transpose_k<true><<<dim3(8, 4, 1), tt, 0, stream>>>(g0w2, DD, 0, 0, 1, nullptr, 0, w20T, HIDC, 0, HIDC, DD);
    transpose_k<true><<<dim3(4, 8, 1), tt, 0, stream>>>(g1w1, HIDC, 0, 0, 1, nullptr, 0, w11T, DD, 0, DD, HIDC);
    transpose_k<true><<<dim3(8, 4, 1), tt, 0, stream>>>(g1w2, DD, 0, 0, 1, nullptr, 0, w21T, HIDC, 0, HIDC, DD);

    // nf = node_feature @ f1_w^T + f1_b    [12000,128]
    gemm128<true, true, true, false, false, false><<<dim3(94, 1), tb, 0, stream>>>(
        nfe, FFEAT, 0, 0, f1w, FFEAT, 0, 0, f1b,
        nf, DD, 0, 0, NN, DD, FFEAT, 1, 1, 1.f, nullptr);
    // BT = (emb .* nf)^T   [128][12000]
    transpose_k<false><<<dim3(375, 4, 1), tt, 0, stream>>>(nf, DD, 0, 0, 1, emb, DD, BT, NN, 0, NN, DD);

    const float* biases2[2] = { g0b2, g1b2 };
    const float* biases1[2] = { g0b1, g1b1 };
    const bf* w1T[2] = { w10T, w11T };
    const bf* w2T[2] = { w20T, w21T };
    bf* xout[2] = { bufP, bufQ };   // x1 -> bufP ; item -> bufQ

    for (int g = 0; g < 2; g++) {
        // t = A @ x  (x^T staged in BT), K-split 5
        if (g == 0) {
            // first adj pass reads f32 adj and side-writes the bf16 copy
            gemm128<true, false, false, false, true, true><<<dim3(94, AZ), tb, 0, stream>>>(
                adj, NN, AKS, 0, BT, NN, AKS, 0, nullptr,
                part, DD, NM, 0, NN, DD, AKS, 1, 1, 1.f, adjb);
        } else {
            adj_gemm7<<<dim3(94, AZ), tb512, 0, stream>>>(adjb, BT, part);
        }
        bf* tbuf = (g == 0) ? bufP : bufQ;
        reduceK<<<dim3((NM + 255) / 256), tb, 0, stream>>>(part, nullptr, tbuf, (int)NM, AZ, NM);
        // h = relu(t @ W1 + b1)   [12000,256]
        gemm128<false, false, true, true, false, false><<<dim3(188, 1), tb, 0, stream>>>(
            tbuf, DD, 0, 0, w1T[g], DD, 0, 0, biases1[g],
            Hbuf, HIDC, 0, 0, NN, HIDC, DD, 2, 1, 1.f, nullptr);
        // t2 = h @ W2            [12000,128]
        bf* t2buf = (g == 0) ? bufQ : bufP;
        gemm128<false, false, false, false, false, false><<<dim3(94, 1), tb, 0, stream>>>(
            Hbuf, HIDC, 0, 0, w2T[g], HIDC, 0, 0, nullptr,
            t2buf, DD, 0, 0, NN, DD, HIDC, 1, 1, 1.f, nullptr);
        // BT = t2^T
        transpose_k<false><<<dim3(375, 4, 1), tt, 0, stream>>>(t2buf, DD, 0, 0, 1, nullptr, 0, BT, NN, 0, NN, DD);
        // x' = A @ t2 + b2  (single-barrier 3-ring adj kernel)
        adj_gemm7<<<dim3(94, AZ), tb512, 0, stream>>>(adjb, BT, part);
        reduceK<<<dim3((NM + 255) / 256), tb, 0, stream>>>(part, biases2[g], xout[g], (int)NM, AZ, NM);
        if (g == 0) {
            // BT = x1^T for next module
            transpose_k<false><<<dim3(375, 4, 1), tt, 0, stream>>>(bufP, DD, 0, 0, 1, nullptr, 0, BT, NN, 0, NN, DD);
        }
    }
    bf* item = bufQ;

    // seq = item[u_seqs]   [10240,128]
    gather_rows<<<dim3(640), tb, 0, stream>>>(item, useqs, seq, 10240);
    // qkv = seq @ in_proj_w^T + b   [10240,384]
    gemm128<false, true, true, false, false, false><<<dim3(240, 1), tb, 0, stream>>>(
        seq, DD, 0, 0, ipw, DD, 0, 0, ipb,
        qkv, 384, 0, 0, 10240, 384, DD, 3, 1, 1.f, nullptr);
    // VT[z=(n,h)][d][t] from qkv V slice
    transpose_k<false><<<dim3(16, 1, 80), tt, 0, stream>>>(
        qkv + 256, 7680, 384, 32, 4, nullptr, 0, VT, 512, 16384, 512, 32);
    // S[z] = alpha * Q_z @ K_z^T   (z = n*4+h), M=N=512, K=32
    gemm128<false, false, false, false, false, false><<<dim3(16, 80), tb, 0, stream>>>(
        qkv, 7680, 384, 32, qkv + 128, 7680, 384, 32, nullptr,
        Sb, 512, (long long)4 * 262144, 262144, 512, 512, 32, 4, 4, 0.17677669529663687f, nullptr);
    // softmax rows (in place)
    softmax512<<<dim3(10240), tb, 0, stream>>>(Sb, 80 * 512);
    // o = P @ V   -> o[s][n][h*32+d]
    gemm128<false, false, false, false, false, false><<<dim3(4, 80), tb, 0, stream>>>(
        Sb, 512, (long long)4 * 262144, 262144, VT, 512, (long long)4 * 16384, 16384, nullptr,
        o_, 2560, 128, 32, 512, 32, 512, 1, 4, 1.f, nullptr);
    // o2 = o @ out_proj^T + b
    gemm128<false, true, true, false, false, false><<<dim3(80, 1), tb, 0, stream>>>(
        o_, DD, 0, 0, opw, DD, 0, 0, opb,
        o2, DD, 0, 0, 10240, DD, DD, 1, 1, 1.f, nullptr);
    // x1 = LN(seq + o2)
    ln_rows<<<dim3(2560), tb, 0, stream>>>(seq, o2, ln1s, ln1b, x1ln, 10240);
    // ffh = relu(x1 @ ff1^T + b)   [10240,512]
    gemm128<false, true, true, true, false, false><<<dim3(320, 1), tb, 0, stream>>>(
        x1ln, DD, 0, 0, ff1w, DD, 0, 0, ff1b,
        ffh, FFDIM, 0, 0, 10240, FFDIM, DD, 4, 1, 1.f, nullptr);
    // ff2 = ffh @ ff2^T + b
    gemm128<false, true, true, false, false, false><<<dim3(80, 1), tb, 0, stream>>>(
        ffh, FFDIM, 0, 0, ff2w, FFDIM, 0, 0, ff2b,
        ff2o, DD, 0, 0, 10240, DD, FFDIM, 1, 1, 1.f, nullptr);
    // x2 = LN(x1 + ff2)
    ln_rows<<<dim3(2560), tb, 0, stream>>>(x1ln, ff2o, ln2s, ln2b, x2, 10240);
    // citing_paper / cited_paper
    build_citing<<<dim3(512), tb, 0, stream>>>(x2, nf, citing, cp);
    build_cited<<<dim3(12000), tb, 0, stream>>>(item, nf, cited);
    // scores = cp @ cited^T   [512,12000]  (f32 out)
    gemm128<false, false, false, false, true, false><<<dim3(376, 1), tb, 0, stream>>>(
        cp, 256, 0, 0, cited, 256, 0, 0, nullptr,
        outp, NN, 0, 0, BBATCH, NN, 256, 94, 1, 1.f, nullptr);
}

// Round 13
// 766.671 us; speedup vs baseline: 1.3293x; 1.0015x over previous
//
#include <hip/hip_runtime.h>
#include <hip/hip_bf16.h>

typedef __hip_bfloat16 bf;
typedef __attribute__((ext_vector_type(4))) float f32x4;
typedef __attribute__((ext_vector_type(8))) __bf16 bf16x8;
typedef __attribute__((ext_vector_type(8))) short short8;

#define NN 12000
#define DD 128
#define HIDC 256
#define BBATCH 512
#define LSEQ 20
#define FFEAT 400
#define FFDIM 512
#define AZ 5
#define AKS (NN / AZ)     // 2400 = 37*64 + 32

__device__ __forceinline__ float b2f(bf v) { return __bfloat162float(v); }
__device__ __forceinline__ bf f2b(float v) { return __float2bfloat16(v); }
__device__ __forceinline__ float us2f(unsigned short u) {
    return __uint_as_float(((unsigned int)u) << 16);
}
__device__ __forceinline__ unsigned short f2us(float f) {
    bf h = __float2bfloat16(f);
    return __builtin_bit_cast(unsigned short, h);
}

__device__ __forceinline__ void gload_lds16(const bf* g, bf* l) {
    __builtin_amdgcn_global_load_lds(
        (__attribute__((address_space(1))) void*)(g),
        (__attribute__((address_space(3))) void*)(l),
        16, 0, 0);
}

template<bool F32>
__device__ __forceinline__ short8 ld8(const void* p, long long idx) {
    if (F32) {
        const float* fp = (const float*)p + idx;
        f32x4 u0 = *(const f32x4*)fp;
        f32x4 u1 = *(const f32x4*)(fp + 4);
        short8 s;
        s[0] = (short)f2us(u0[0]); s[1] = (short)f2us(u0[1]);
        s[2] = (short)f2us(u0[2]); s[3] = (short)f2us(u0[3]);
        s[4] = (short)f2us(u1[0]); s[5] = (short)f2us(u1[1]);
        s[6] = (short)f2us(u1[2]); s[7] = (short)f2us(u1[3]);
        return s;
    } else {
        return *(const short8*)((const bf*)p + idx);
    }
}

template<bool F32>
__device__ __forceinline__ bf ldelem(const void* p, long long idx) {
    if (F32) return f2b(((const float*)p)[idx]);
    return ((const bf*)p)[idx];
}

// ---------------------------------------------------------------------------
// adj pass v8: BK=64, 4-buffer LDS ring, prefetch distance 3 (vs 2 in v7).
// Hypothesis from R11/R12 fits: step_time ~= T_tile_load / prefetch_depth;
// depth 2 gave 2.26us/step, depth 3 should give ~1.5us/step.
// One barrier per step (v7-verified). Race: stage(t+3) -> buf((t+3)&3) ==
// buf((t-1)&3), last read at t-1; issuing wave is past barrier t => all
// waves finished step t-1 reads. LDS 128 KB (4buf x 16KB x 2 matrices),
// 512 threads, 1 block/CU. Swizzles identical to R11-verified v6/v7.
// vmcnt ladder: 8 steady (2 future stages x 4 issues), 6, 2, 0 at tail.
// ---------------------------------------------------------------------------
__global__ __launch_bounds__(512) void adj_gemm8(
    const bf* __restrict__ A,    // adjb [NN][NN]
    const bf* __restrict__ Bt,   // BT [128][NN]
    float* __restrict__ part)    // [AZ][NN][128]
{
    alignas(16) __shared__ bf As[4][128 * 64];
    alignas(16) __shared__ bf Bs[4][128 * 64];
    const int tid = threadIdx.x;
    const int lane = tid & 63;
    const int w = tid >> 6;                       // 0..7
    const int z = blockIdx.y;
    const long long k0 = (long long)z * AKS;
    int m0 = blockIdx.x * 128;
    if (m0 > NN - 128) m0 = NN - 128;

    // full-stage staging: wave w covers rows 16w..16w+15 of A and of B
    // (2 issues each); lane L -> row rbase+(L>>3), source chunk (L&7)^(L>>3)
    const int rowi = lane >> 3;
    const int chks = (lane & 7) ^ rowi;
    const bf* gA[2]; const bf* gB[2]; int lo[2];
    #pragma unroll
    for (int i = 0; i < 2; i++) {
        int rbase = 16 * w + 8 * i;
        gA[i] = A  + (long long)(m0 + rbase + rowi) * NN + k0 + chks * 8;
        gB[i] = Bt + (long long)(rbase + rowi) * NN + k0 + chks * 8;
        lo[i] = rbase * 64;
    }
    // tail staging (last 32 cols): 16 rows/issue, R4 swizzle, compact region
    // at the start of buffer 1 (full region of buf1 last read at t=33)
    const int rowiT = lane >> 2;
    const int chksT = (lane & 3) ^ ((lane >> 3) & 3);
    const bf* gAT = A  + (long long)(m0 + 16 * w + rowiT) * NN + k0 + 2368 + chksT * 8;
    const bf* gBT = Bt + (long long)(16 * w + rowiT) * NN + k0 + 2368 + chksT * 8;
    const int loT = (16 * w) * 32;

    const int wr = (w >> 1) * 32, wc = (w & 1) * 64;
    const int fr = lane & 15;
    const int kq = lane >> 4;
    int aoff[2][2], boff[2][4], aoffT[2], boffT[4];
    #pragma unroll
    for (int mi = 0; mi < 2; mi++) {
        int ra = wr + mi * 16 + fr;
        aoff[0][mi] = ra * 64 + ((kq)     ^ (ra & 7)) * 8;
        aoff[1][mi] = ra * 64 + ((4 + kq) ^ (ra & 7)) * 8;
        aoffT[mi]   = ra * 32 + (kq ^ ((ra >> 1) & 3)) * 8;
    }
    #pragma unroll
    for (int ni = 0; ni < 4; ni++) {
        int rb = wc + ni * 16 + fr;
        boff[0][ni] = rb * 64 + ((kq)     ^ (rb & 7)) * 8;
        boff[1][ni] = rb * 64 + ((4 + kq) ^ (rb & 7)) * 8;
        boffT[ni]   = rb * 32 + (kq ^ ((rb >> 1) & 3)) * 8;
    }
    f32x4 acc[2][4] = {};

    auto stage64 = [&](int t, int b) {
        const long long go = (long long)t * 64;
        const int bo = b * (128 * 64);
        #pragma unroll
        for (int i = 0; i < 2; i++) {
            gload_lds16(gA[i] + go, &As[0][0] + bo + lo[i]);
            gload_lds16(gB[i] + go, &Bs[0][0] + bo + lo[i]);
        }
    };
    auto stageTail = [&]() {
        gload_lds16(gAT, &As[1][0] + loT);
        gload_lds16(gBT, &Bs[1][0] + loT);
    };
    auto compute64 = [&](int b) {
        const bf* Ab = &As[0][0] + b * (128 * 64);
        const bf* Bb = &Bs[0][0] + b * (128 * 64);
        #pragma unroll
        for (int s = 0; s < 2; s++) {
            bf16x8 af[2], bfr[4];
            #pragma unroll
            for (int mi = 0; mi < 2; mi++) af[mi]  = *(const bf16x8*)(Ab + aoff[s][mi]);
            #pragma unroll
            for (int ni = 0; ni < 4; ni++) bfr[ni] = *(const bf16x8*)(Bb + boff[s][ni]);
            #pragma unroll
            for (int mi = 0; mi < 2; mi++)
                #pragma unroll
                for (int ni = 0; ni < 4; ni++)
                    acc[mi][ni] = __builtin_amdgcn_mfma_f32_16x16x32_bf16(
                        af[mi], bfr[ni], acc[mi][ni], 0, 0, 0);
        }
    };

    // prologue: 3 stages in flight (12 issues/wave)
    stage64(0, 0);
    stage64(1, 1);
    stage64(2, 2);

    #pragma unroll 1
    for (int t = 0; t < 35; t++) {
        asm volatile("s_waitcnt vmcnt(8)" ::: "memory");   // stage t resident
        __builtin_amdgcn_s_barrier();                      // all waves' stages landed
        __builtin_amdgcn_sched_barrier(0);
        compute64(t & 3);
        if (t < 34) stage64(t + 3, (t + 3) & 3);           // overwrites buf read at t-1
        else        stageTail();                           // t=34: stage 37 -> buf1 compact
    }
    // t = 35 (buf 3): outstanding = stage36 (4) + tail (2)
    asm volatile("s_waitcnt vmcnt(6)" ::: "memory");
    __builtin_amdgcn_s_barrier();
    __builtin_amdgcn_sched_barrier(0);
    compute64(3);
    // t = 36 (buf 0): outstanding = tail (2)
    asm volatile("s_waitcnt vmcnt(2)" ::: "memory");
    __builtin_amdgcn_s_barrier();
    __builtin_amdgcn_sched_barrier(0);
    compute64(0);
    // t = 37: tail (buf1 compact)
    asm volatile("s_waitcnt vmcnt(0)" ::: "memory");
    __builtin_amdgcn_s_barrier();
    __builtin_amdgcn_sched_barrier(0);
    {
        bf16x8 af[2], bfr[4];
        #pragma unroll
        for (int mi = 0; mi < 2; mi++) af[mi]  = *(const bf16x8*)(&As[1][0] + aoffT[mi]);
        #pragma unroll
        for (int ni = 0; ni < 4; ni++) bfr[ni] = *(const bf16x8*)(&Bs[1][0] + boffT[ni]);
        #pragma unroll
        for (int mi = 0; mi < 2; mi++)
            #pragma unroll
            for (int ni = 0; ni < 4; ni++)
                acc[mi][ni] = __builtin_amdgcn_mfma_f32_16x16x32_bf16(
                    af[mi], bfr[ni], acc[mi][ni], 0, 0, 0);
    }

    float* C = part + (long long)z * ((long long)NN * 128);
    const int cr0 = (lane >> 4) * 4;
    const int cc = lane & 15;
    #pragma unroll
    for (int mi = 0; mi < 2; mi++) {
        #pragma unroll
        for (int ni = 0; ni < 4; ni++) {
            int col = wc + ni * 16 + cc;
            #pragma unroll
            for (int j = 0; j < 4; j++) {
                int row = m0 + wr + mi * 16 + cr0 + j;
                C[(long long)row * 128 + col] = acc[mi][ni][j];
            }
        }
    }
}

// ---------------------------------------------------------------------------
// Generic batched MFMA GEMM: C = act(alpha * A @ B^T + bias)
// ---------------------------------------------------------------------------
template<bool A_F32, bool B_F32, bool HAS_BIAS, bool RELU, bool OUT_F32, bool SIDE_A>
__global__ __launch_bounds__(256) void gemm128(
    const void* __restrict__ A, int lda, long long sA1, long long sA2,
    const void* __restrict__ Bm, int ldb, long long sB1, long long sB2,
    const float* __restrict__ bias,
    void* __restrict__ Cv, int ldc, long long sC1, long long sC2,
    int M, int N, int K, int tilesN, int zdiv, float alpha,
    bf* __restrict__ sideA)
{
    __shared__ bf As[128][40];
    __shared__ bf Bs[128][40];
    const int tid = threadIdx.x;
    const int z = blockIdx.y;
    const int zq = z / zdiv, zr = z - zq * zdiv;
    const char* Ap = (const char*)A;
    const char* Bp = (const char*)Bm;
    const long long offA = (long long)zq * sA1 + (long long)zr * sA2;
    const long long offB = (long long)zq * sB1 + (long long)zr * sB2;
    const long long offC = (long long)zq * sC1 + (long long)zr * sC2;
    const int tm = blockIdx.x / tilesN, tn = blockIdx.x - tm * tilesN;
    int m0 = tm * 128; if (m0 > M - 128) m0 = M - 128;
    const int n0 = tn * 128;
    const int lane = tid & 63;
    const int wv = tid >> 6;
    const int wr = (wv >> 1) * 64, wc = (wv & 1) * 64;
    const int fr = lane & 15;
    const int kq = (lane >> 4) * 8;
    const int sr = tid >> 2, scol = (tid & 3) * 8;
    f32x4 acc[4][4] = {};

    for (int k0 = 0; k0 < K; k0 += 32) {
        if (k0 + 32 <= K) {
            const long long ia0 = offA + (long long)(m0 + sr) * lda + k0 + scol;
            const long long ia1 = offA + (long long)(m0 + sr + 64) * lda + k0 + scol;
            short8 va0 = ld8<A_F32>(Ap, ia0);
            short8 va1 = ld8<A_F32>(Ap, ia1);
            short8 vb0 = {0,0,0,0,0,0,0,0}, vb1 = {0,0,0,0,0,0,0,0};
            if (n0 + sr < N)      vb0 = ld8<B_F32>(Bp, offB + (long long)(n0 + sr) * ldb + k0 + scol);
            if (n0 + sr + 64 < N) vb1 = ld8<B_F32>(Bp, offB + (long long)(n0 + sr + 64) * ldb + k0 + scol);
            if (SIDE_A) {
                *(short8*)&sideA[ia0] = va0;
                *(short8*)&sideA[ia1] = va1;
            }
            *(short8*)&As[sr][scol] = va0;
            *(short8*)&As[sr + 64][scol] = va1;
            *(short8*)&Bs[sr][scol] = vb0;
            *(short8*)&Bs[sr + 64][scol] = vb1;
        } else {
            bf zv = f2b(0.f);
            for (int i = tid; i < 128 * 32; i += 256) {
                int r = i >> 5, c = i & 31, gk = k0 + c;
                As[r][c] = (gk < K) ? ldelem<A_F32>(Ap, offA + (long long)(m0 + r) * lda + gk) : zv;
                Bs[r][c] = (gk < K && n0 + r < N) ? ldelem<B_F32>(Bp, offB + (long long)(n0 + r) * ldb + gk) : zv;
            }
        }
        __syncthreads();
        bf16x8 af[4], bfg[4];
        #pragma unroll
        for (int i = 0; i < 4; i++) af[i]  = *(const bf16x8*)&As[wr + i * 16 + fr][kq];
        #pragma unroll
        for (int i = 0; i < 4; i++) bfg[i] = *(const bf16x8*)&Bs[wc + i * 16 + fr][kq];
        #pragma unroll
        for (int mi = 0; mi < 4; mi++)
            #pragma unroll
            for (int ni = 0; ni < 4; ni++)
                acc[mi][ni] = __builtin_amdgcn_mfma_f32_16x16x32_bf16(
                    af[mi], bfg[ni], acc[mi][ni], 0, 0, 0);
        __syncthreads();
    }

    const int cr0 = (lane >> 4) * 4;
    const int cc = lane & 15;
    #pragma unroll
    for (int mi = 0; mi < 4; mi++) {
        #pragma unroll
        for (int ni = 0; ni < 4; ni++) {
            int col = n0 + wc + ni * 16 + cc;
            if (col >= N) continue;
            float bv = 0.f;
            if (HAS_BIAS) bv = bias[col];
            #pragma unroll
            for (int j = 0; j < 4; j++) {
                int row = m0 + wr + mi * 16 + cr0 + j;
                float v = acc[mi][ni][j] * alpha + bv;
                if (RELU) v = fmaxf(v, 0.f);
                if (OUT_F32) ((float*)Cv)[offC + (long long)row * ldc + col] = v;
                else ((bf*)Cv)[offC + (long long)row * ldc + col] = f2b(v);
            }
        }
    }
}

template<bool IN_F32>
__global__ __launch_bounds__(256) void transpose_k(
    const void* __restrict__ in, int ldin, long long sI1, long long sI2, int zdiv,
    const float* __restrict__ mulp, int ldmul,
    bf* __restrict__ outp, int ldout, long long sOut,
    int R, int C)
{
    __shared__ bf t[32][33];
    const int z = blockIdx.z;
    const int zq = z / zdiv, zr = z - zq * zdiv;
    const long long offI = (long long)zq * sI1 + (long long)zr * sI2;
    bf* op = outp + (long long)z * sOut;
    int r0 = blockIdx.x * 32, c0 = blockIdx.y * 32;
    int tx = threadIdx.x, ty = threadIdx.y;   // 32 x 8
    #pragma unroll
    for (int i = 0; i < 4; i++) {
        int r = r0 + ty + i * 8, c = c0 + tx;
        bf v = f2b(0.f);
        if (r < R && c < C) {
            v = ldelem<IN_F32>(in, offI + (long long)r * ldin + c);
            if (mulp) v = f2b(b2f(v) * mulp[(long long)r * ldmul + c]);
        }
        t[ty + i * 8][tx] = v;
    }
    __syncthreads();
    #pragma unroll
    for (int i = 0; i < 4; i++) {
        int c = c0 + ty + i * 8, r = r0 + tx;
        if (c < C && r < R) op[(long long)c * ldout + r] = t[tx][ty + i * 8];
    }
}

__global__ __launch_bounds__(256) void reduceK(
    const float* __restrict__ part, const float* __restrict__ bias,
    bf* __restrict__ outp, int total, int nz, long long zs)
{
    int i = blockIdx.x * 256 + threadIdx.x;
    if (i >= total) return;
    float s = 0.f;
    for (int zz = 0; zz < nz; zz++) s += part[(long long)zz * zs + i];
    if (bias) s += bias[i & 127];
    outp[i] = f2b(s);
}

__global__ __launch_bounds__(256) void gather_rows(
    const bf* __restrict__ src, const int* __restrict__ idx,
    bf* __restrict__ dst, int nrows)
{
    int t = blockIdx.x * 256 + threadIdx.x;
    int row = t >> 4, p = t & 15;
    if (row >= nrows) return;
    long long srow = idx[row];
    *(short8*)&dst[(long long)row * 128 + p * 8] =
        *(const short8*)&src[srow * 128 + p * 8];
}

__global__ __launch_bounds__(256) void softmax512(bf* __restrict__ S, int nrows)
{
    int gid = blockIdx.x * 256 + threadIdx.x;
    int wid = gid >> 6, lane = gid & 63;
    if (wid >= nrows) return;
    bf* row = S + (long long)wid * 512;
    short8 raw = *(const short8*)&row[lane * 8];
    float v[8];
    float mx = -3.0e38f;
    #pragma unroll
    for (int j = 0; j < 8; j++) {
        v[j] = us2f((unsigned short)raw[j]);
        mx = fmaxf(mx, v[j]);
    }
    #pragma unroll
    for (int off = 32; off; off >>= 1) mx = fmaxf(mx, __shfl_xor(mx, off, 64));
    float sum = 0.f;
    #pragma unroll
    for (int j = 0; j < 8; j++) { v[j] = __expf(v[j] - mx); sum += v[j]; }
    #pragma unroll
    for (int off = 32; off; off >>= 1) sum += __shfl_xor(sum, off, 64);
    float inv = 1.f / sum;
    short8 o;
    #pragma unroll
    for (int j = 0; j < 8; j++) o[j] = (short)f2us(v[j] * inv);
    *(short8*)&row[lane * 8] = o;
}

__global__ __launch_bounds__(256) void ln_rows(
    const bf* __restrict__ a, const bf* __restrict__ bres,
    const float* __restrict__ sc, const float* __restrict__ bi,
    bf* __restrict__ outp, int nrows)
{
    int gid = blockIdx.x * 256 + threadIdx.x;
    int wid = gid >> 6, lane = gid & 63;
    if (wid >= nrows) return;
    long long base = (long long)wid * 128;
    int i0 = lane * 2, i1 = lane * 2 + 1;
    float x0 = b2f(a[base + i0]) + b2f(bres[base + i0]);
    float x1 = b2f(a[base + i1]) + b2f(bres[base + i1]);
    float s = x0 + x1;
    #pragma unroll
    for (int off = 32; off; off >>= 1) s += __shfl_xor(s, off, 64);
    float mean = s * (1.f / 128.f);
    float d0 = x0 - mean, d1 = x1 - mean;
    float vv = d0 * d0 + d1 * d1;
    #pragma unroll
    for (int off = 32; off; off >>= 1) vv += __shfl_xor(vv, off, 64);
    float inv = rsqrtf(vv * (1.f / 128.f) + 1e-5f);
    outp[base + i0] = f2b(d0 * inv * sc[i0] + bi[i0]);
    outp[base + i1] = f2b(d1 * inv * sc[i1] + bi[i1]);
}

__global__ __launch_bounds__(256) void build_citing(
    const bf* __restrict__ x2, const bf* __restrict__ nf,
    const int* __restrict__ citing, bf* __restrict__ cp)
{
    int i = blockIdx.x * 256 + threadIdx.x;
    if (i >= BBATCH * 256) return;
    int b = i >> 8, d = i & 255;
    float v;
    if (d < 128) {
        float s = 0.f;
        for (int l = 0; l < LSEQ; l++)
            s += b2f(x2[((long long)b * LSEQ + l) * 128 + d]);
        v = s * (1.f / (float)LSEQ);
    } else {
        v = b2f(nf[(long long)citing[b] * 128 + (d - 128)]);
    }
    cp[i] = f2b(v);
}

__global__ __launch_bounds__(256) void build_cited(
    const bf* __restrict__ item, const bf* __restrict__ nf, bf* __restrict__ outp)
{
    int i = blockIdx.x * 256 + threadIdx.x;
    if (i >= NN * 256) return;
    int r = i >> 8, d = i & 255;
    outp[i] = (d < 128) ? item[(long long)r * 128 + d]
                        : nf[(long long)r * 128 + (d - 128)];
}

// ---------------------------------------------------------------------------
extern "C" void kernel_launch(void* const* d_in, const int* in_sizes, int n_in,
                              void* d_out, int out_size, void* d_ws, size_t ws_size,
                              hipStream_t stream)
{
    const float* emb  = (const float*)d_in[0];
    const float* f1w  = (const float*)d_in[1];
    const float* f1b  = (const float*)d_in[2];
    const float* g0w1 = (const float*)d_in[3];  const float* g0b1 = (const float*)d_in[4];
    const float* g0w2 = (const float*)d_in[5];  const float* g0b2 = (const float*)d_in[6];
    const float* g1w1 = (const float*)d_in[7];  const float* g1b1 = (const float*)d_in[8];
    const float* g1w2 = (const float*)d_in[9];  const float* g1b2 = (const float*)d_in[10];
    const float* ipw  = (const float*)d_in[11]; const float* ipb  = (const float*)d_in[12];
    const float* opw  = (const float*)d_in[13]; const float* opb  = (const float*)d_in[14];
    const float* ln1s = (const float*)d_in[15]; const float* ln1b = (const float*)d_in[16];
    const float* ff1w = (const float*)d_in[17]; const float* ff1b = (const float*)d_in[18];
    const float* ff2w = (const float*)d_in[19]; const float* ff2b = (const float*)d_in[20];
    const float* ln2s = (const float*)d_in[21]; const float* ln2b = (const float*)d_in[22];
    const float* adj  = (const float*)d_in[23];
    const float* nfe  = (const float*)d_in[24];
    const int* citing = (const int*)d_in[26];
    const int* useqs  = (const int*)d_in[28];
    float* outp = (float*)d_out;

    size_t off = 0;
    auto carve = [&](size_t bytes) -> char* {
        char* p = (char*)d_ws + off;
        off += (bytes + 255) & ~(size_t)255;
        return p;
    };
    bf* adjb = (bf*)carve((size_t)NN * NN * 2);       // bf16 copy of adj (288 MB)
    bf* nf   = (bf*)carve((size_t)NN * DD * 2);
    bf* bufP = (bf*)carve((size_t)NN * DD * 2);
    bf* bufQ = (bf*)carve((size_t)NN * DD * 2);
    bf* BT   = (bf*)carve((size_t)NN * DD * 2);       // transposed [128][12000]
    bf* Hbuf = (bf*)carve((size_t)NN * HIDC * 2);
    float* part = (float*)carve((size_t)AZ * NN * DD * 4);   // 30 MB
    bf* seq  = (bf*)carve((size_t)10240 * DD * 2);
    bf* qkv  = (bf*)carve((size_t)10240 * 384 * 2);
    bf* Sb   = (bf*)carve((size_t)80 * 512 * 512 * 2);
    bf* w10T = (bf*)carve((size_t)DD * HIDC * 2);
    bf* w20T = (bf*)carve((size_t)DD * HIDC * 2);
    bf* w11T = (bf*)carve((size_t)DD * HIDC * 2);
    bf* w21T = (bf*)carve((size_t)DD * HIDC * 2);
    // aliases (regions dead by the time these are live)
    bf* x1ln = (bf*)Hbuf;
    bf* cp   = (bf*)((char*)Hbuf + (size_t)10240 * DD * 2);
    char* pr = (char*)part;
    bf* VT   = (bf*)pr; pr += (size_t)80 * 32 * 512 * 2;
    bf* o_   = (bf*)pr; pr += (size_t)10240 * DD * 2;
    bf* o2   = (bf*)pr; pr += (size_t)10240 * DD * 2;
    bf* ffh  = (bf*)pr; pr += (size_t)10240 * FFDIM * 2;
    bf* ff2o = (bf*)pr; pr += (size_t)10240 * DD * 2;
    bf* x2   = (bf*)pr; pr += (size_t)10240 * DD * 2;
    bf* cited= (bf*)pr; pr += (size_t)NN * 256 * 2;

    dim3 tb(256), tb512(512), tt(32, 8);
    const long long NM = (long long)NN * DD;   // 1,536,000

    // GCN weight transposes: W1[D,HID] -> w1T[HID,D];  W2[HID,D] -> w2T[D,HID]
    transpose_k<true><<<dim3(4, 8, 1), tt, 0, stream>>>(g0w1, HIDC, 0, 0, 1, nullptr, 0, w10T, DD, 0, DD, HIDC);
    transpose_k<true><<<dim3(8, 4, 1), tt, 0, stream>>>(g0w2, DD, 0, 0, 1, nullptr, 0, w20T, HIDC, 0, HIDC, DD);
    transpose_k<true><<<dim3(4, 8, 1), tt, 0, stream>>>(g1w1, HIDC, 0, 0, 1, nullptr, 0, w11T, DD, 0, DD, HIDC);
    transpose_k<true><<<dim3(8, 4, 1), tt, 0, stream>>>(g1w2, DD, 0, 0, 1, nullptr, 0, w21T, HIDC, 0, HIDC, DD);

    // nf = node_feature @ f1_w^T + f1_b    [12000,128]
    gemm128<true, true, true, false, false, false><<<dim3(94, 1), tb, 0, stream>>>(
        nfe, FFEAT, 0, 0, f1w, FFEAT, 0, 0, f1b,
        nf, DD, 0, 0, NN, DD, FFEAT, 1, 1, 1.f, nullptr);
    // BT = (emb .* nf)^T   [128][12000]
    transpose_k<false><<<dim3(375, 4, 1), tt, 0, stream>>>(nf, DD, 0, 0, 1, emb, DD, BT, NN, 0, NN, DD);

    const float* biases2[2] = { g0b2, g1b2 };
    const float* biases1[2] = { g0b1, g1b1 };
    const bf* w1T[2] = { w10T, w11T };
    const bf* w2T[2] = { w20T, w21T };
    bf* xout[2] = { bufP, bufQ };   // x1 -> bufP ; item -> bufQ

    for (int g = 0; g < 2; g++) {
        // t = A @ x  (x^T staged in BT), K-split 5
        if (g == 0) {
            // first adj pass reads f32 adj and side-writes the bf16 copy
            gemm128<true, false, false, false, true, true><<<dim3(94, AZ), tb, 0, stream>>>(
                adj, NN, AKS, 0, BT, NN, AKS, 0, nullptr,
                part, DD, NM, 0, NN, DD, AKS, 1, 1, 1.f, adjb);
        } else {
            adj_gemm8<<<dim3(94, AZ), tb512, 0, stream>>>(adjb, BT, part);
        }
        bf* tbuf = (g == 0) ? bufP : bufQ;
        reduceK<<<dim3((NM + 255) / 256), tb, 0, stream>>>(part, nullptr, tbuf, (int)NM, AZ, NM);
        // h = relu(t @ W1 + b1)   [12000,256]
        gemm128<false, false, true, true, false, false><<<dim3(188, 1), tb, 0, stream>>>(
            tbuf, DD, 0, 0, w1T[g], DD, 0, 0, biases1[g],
            Hbuf, HIDC, 0, 0, NN, HIDC, DD, 2, 1, 1.f, nullptr);
        // t2 = h @ W2            [12000,128]
        bf* t2buf = (g == 0) ? bufQ : bufP;
        gemm128<false, false, false, false, false, false><<<dim3(94, 1), tb, 0, stream>>>(
            Hbuf, HIDC, 0, 0, w2T[g], HIDC, 0, 0, nullptr,
            t2buf, DD, 0, 0, NN, DD, HIDC, 1, 1, 1.f, nullptr);
        // BT = t2^T
        transpose_k<false><<<dim3(375, 4, 1), tt, 0, stream>>>(t2buf, DD, 0, 0, 1, nullptr, 0, BT, NN, 0, NN, DD);
        // x' = A @ t2 + b2  (4-ring depth-3 adj kernel)
        adj_gemm8<<<dim3(94, AZ), tb512, 0, stream>>>(adjb, BT, part);
        reduceK<<<dim3((NM + 255) / 256), tb, 0, stream>>>(part, biases2[g], xout[g], (int)NM, AZ, NM);
        if (g == 0) {
            // BT = x1^T for next module
            transpose_k<false><<<dim3(375, 4, 1), tt, 0, stream>>>(bufP, DD, 0, 0, 1, nullptr, 0, BT, NN, 0, NN, DD);
        }
    }
    bf* item = bufQ;

    // seq = item[u_seqs]   [10240,128]
    gather_rows<<<dim3(640), tb, 0, stream>>>(item, useqs, seq, 10240);
    // qkv = seq @ in_proj_w^T + b   [10240,384]
    gemm128<false, true, true, false, false, false><<<dim3(240, 1), tb, 0, stream>>>(
        seq, DD, 0, 0, ipw, DD, 0, 0, ipb,
        qkv, 384, 0, 0, 10240, 384, DD, 3, 1, 1.f, nullptr);
    // VT[z=(n,h)][d][t] from qkv V slice
    transpose_k<false><<<dim3(16, 1, 80), tt, 0, stream>>>(
        qkv + 256, 7680, 384, 32, 4, nullptr, 0, VT, 512, 16384, 512, 32);
    // S[z] = alpha * Q_z @ K_z^T   (z = n*4+h), M=N=512, K=32
    gemm128<false, false, false, false, false, false><<<dim3(16, 80), tb, 0, stream>>>(
        qkv, 7680, 384, 32, qkv + 128, 7680, 384, 32, nullptr,
        Sb, 512, (long long)4 * 262144, 262144, 512, 512, 32, 4, 4, 0.17677669529663687f, nullptr);
    // softmax rows (in place)
    softmax512<<<dim3(10240), tb, 0, stream>>>(Sb, 80 * 512);
    // o = P @ V   -> o[s][n][h*32+d]
    gemm128<false, false, false, false, false, false><<<dim3(4, 80), tb, 0, stream>>>(
        Sb, 512, (long long)4 * 262144, 262144, VT, 512, (long long)4 * 16384, 16384, nullptr,
        o_, 2560, 128, 32, 512, 32, 512, 1, 4, 1.f, nullptr);
    // o2 = o @ out_proj^T + b
    gemm128<false, true, true, false, false, false><<<dim3(80, 1), tb, 0, stream>>>(
        o_, DD, 0, 0, opw, DD, 0, 0, opb,
        o2, DD, 0, 0, 10240, DD, DD, 1, 1, 1.f, nullptr);
    // x1 = LN(seq + o2)
    ln_rows<<<dim3(2560), tb, 0, stream>>>(seq, o2, ln1s, ln1b, x1ln, 10240);
    // ffh = relu(x1 @ ff1^T + b)   [10240,512]
    gemm128<false, true, true, true, false, false><<<dim3(320, 1), tb, 0, stream>>>(
        x1ln, DD, 0, 0, ff1w, DD, 0, 0, ff1b,
        ffh, FFDIM, 0, 0, 10240, FFDIM, DD, 4, 1, 1.f, nullptr);
    // ff2 = ffh @ ff2^T + b
    gemm128<false, true, true, false, false, false><<<dim3(80, 1), tb, 0, stream>>>(
        ffh, FFDIM, 0, 0, ff2w, FFDIM, 0, 0, ff2b,
        ff2o, DD, 0, 0, 10240, DD, FFDIM, 1, 1, 1.f, nullptr);
    // x2 = LN(x1 + ff2)
    ln_rows<<<dim3(2560), tb, 0, stream>>>(x1ln, ff2o, ln2s, ln2b, x2, 10240);
    // citing_paper / cited_paper
    build_citing<<<dim3(512), tb, 0, stream>>>(x2, nf, citing, cp);
    build_cited<<<dim3(12000), tb, 0, stream>>>(item, nf, cited);
    // scores = cp @ cited^T   [512,12000]  (f32 out)
    gemm128<false, false, false, false, true, false><<<dim3(376, 1), tb, 0, stream>>>(
        cp, 256, 0, 0, cited, 256, 0, 0, nullptr,
        outp, NN, 0, 0, BBATCH, NN, 256, 94, 1, 1.f, nullptr);
}